// Round 9
// baseline (1608.809 us; speedup 1.0000x reference)
//
#include <hip/hip_runtime.h>
#include <hip/hip_bf16.h>

typedef float  f32x4  __attribute__((ext_vector_type(4)));
typedef __bf16 bf16x8 __attribute__((ext_vector_type(8)));
typedef __bf16 bf16x4 __attribute__((ext_vector_type(4)));

__device__ __forceinline__ float silu_f(float x) { return x / (1.0f + __expf(-x)); }

__device__ __forceinline__ void gload16(const __bf16* g, const char* lds) {
    __builtin_amdgcn_global_load_lds((const __attribute__((address_space(1))) void*)g,
                                     (__attribute__((address_space(3))) void*)lds, 16, 0, 0);
}

__device__ __forceinline__ bf16x8 ds_read16(unsigned addr) {
    bf16x8 d;
    asm volatile("ds_read_b128 %0, %1" : "=v"(d) : "v"(addr));
    return d;
}

// ---------------- LayerNorm -> bf16 ----------------
__global__ __launch_bounds__(256) void ln_kernel(const float* __restrict__ x,
                                                 const float* __restrict__ g,
                                                 const float* __restrict__ b,
                                                 __bf16* __restrict__ out) {
    int row = blockIdx.x;
    const float* xr = x + (long)row * 1024;
    int t = threadIdx.x;
    f32x4 v = *(const f32x4*)(xr + t * 4);
    float s  = v[0] + v[1] + v[2] + v[3];
    float ss = v[0]*v[0] + v[1]*v[1] + v[2]*v[2] + v[3]*v[3];
    #pragma unroll
    for (int off = 32; off > 0; off >>= 1) {
        s  += __shfl_down(s, off);
        ss += __shfl_down(ss, off);
    }
    __shared__ float red[8];
    int wave = t >> 6, lane = t & 63;
    if (lane == 0) { red[wave*2] = s; red[wave*2+1] = ss; }
    __syncthreads();
    float S  = red[0] + red[2] + red[4] + red[6];
    float SS = red[1] + red[3] + red[5] + red[7];
    float mean = S * (1.0f/1024.0f);
    float var  = SS * (1.0f/1024.0f) - mean*mean;
    float rstd = rsqrtf(var + 1e-5f);
    __bf16* orow = out + (long)row * 1024;
    #pragma unroll
    for (int j = 0; j < 4; j++) {
        float fv = (v[j] - mean) * rstd * g[t*4+j] + b[t*4+j];
        orow[t*4+j] = (__bf16)fv;
    }
}

// ---------------- T5 relative bias matrix (256x256, fp32) ----------------
__global__ __launch_bounds__(256) void relbias_kernel(const float* __restrict__ rel_emb,
                                                      float* __restrict__ bmat) {
    int idx = blockIdx.x * 256 + threadIdx.x;
    int i = idx >> 8, j = idx & 255;
    int n = i - j;
    int ret = (n < 0) ? 16 : 0;
    int an = (n < 0) ? -n : n;
    int bucket;
    if (an < 8) {
        bucket = ret + an;
    } else {
        float vl = logf((float)an * 0.125f) / 2.772588722239781f * 8.0f;
        int lv = 8 + (int)vl;
        bucket = ret + (lv < 15 ? lv : 15);
    }
    bmat[idx] = rel_emb[bucket] * 11.313708498984761f;
}

// ---------------- transpose (rows x cols) fp32 -> bf16 (cols x rows) ----------------
__global__ __launch_bounds__(256) void transpose_kernel(const float* __restrict__ in,
                                                        __bf16* __restrict__ out,
                                                        int rows, int cols) {
    __shared__ __bf16 tile[32][33];
    int c0 = blockIdx.x * 32, r0 = blockIdx.y * 32;
    int lx = threadIdx.x, ly = threadIdx.y;
    #pragma unroll
    for (int i = 0; i < 4; i++) {
        int r = ly + i*8;
        tile[r][lx] = (__bf16)in[(long)(r0 + r) * cols + c0 + lx];
    }
    __syncthreads();
    #pragma unroll
    for (int i = 0; i < 4; i++) {
        int c = ly + i*8;
        out[(long)(c0 + c) * rows + r0 + lx] = tile[lx][c];
    }
}

// ---------------- reduce 8 bf16 partials -> bf16 ----------------
__global__ __launch_bounds__(256) void reduce8_kernel(const __bf16* __restrict__ in,
                                                      __bf16* __restrict__ out) {
    int i = (blockIdx.x * 256 + threadIdx.x) * 4;
    int b = i >> 18;
    int r = i & 262143;
    float s0 = 0.f, s1 = 0.f, s2 = 0.f, s3 = 0.f;
    #pragma unroll
    for (int c = 0; c < 8; ++c) {
        bf16x4 v = *(const bf16x4*)(in + ((long)(b*8 + c) << 18) + r);
        s0 += (float)v[0]; s1 += (float)v[1]; s2 += (float)v[2]; s3 += (float)v[3];
    }
    bf16x4 o; o[0] = (__bf16)s0; o[1] = (__bf16)s1; o[2] = (__bf16)s2; o[3] = (__bf16)s3;
    *(bf16x4*)(out + i) = o;
}

// ================= 256x256 GEMM v2: BK=32, 64KB LDS, 2 blocks/CU =================
// C[m][n] = sum_k A[m][k]*B[n][k]; A: MxK row-major, B: NxK row-major, K = nT*32.
// 8 waves (2Mx4N), per-wave 128x64 (8x4 frags of 16x16x32; 32 MFMA/tile/wave).
// LDS 64KB = 2 slots x (A 16KB + B 16KB), layout row*64B with XOR swizzle
// colbyte ^= ((row&3)<<4) (r4-proven: pre-swizzled global source + swizzled read).
// Per tile: {12 ds_reads; lgkm(4); MFMA mb0-3; lgkm(0); barrier; STAGE t+2 -> this
// slot; MFMA mb4-7 (reg-only, overlaps DMA); vmcnt(4); barrier}. 2 barriers/tile.
struct G2 {
    const __bf16 *A, *B;
    int lda, ldb, nT;
    float* outF;
    __bf16 *o0, *o1;
    const float *c0, *c1;
};

template<int EPI>
__global__ __launch_bounds__(512, 4) void gemm256v2(G2 p) {
    __shared__ __align__(128) char smem[65536];
    const int tid = threadIdx.x;
    const int wave = tid >> 6, lane = tid & 63;
    const int wr = (wave >> 2) * 128, wc = (wave & 3) * 64;
    const int lr = lane & 15, kg = lane >> 4;

    // XCD-bijective swizzle (nwg % 8 == 0 for our launches)
    const int gx = gridDim.x, gy = gridDim.y;
    int f = blockIdx.y * gx + blockIdx.x;
    int cpx = (gx * gy) >> 3;
    int s8 = (f & 7) * cpx + (f >> 3);
    int bx = s8 / gy, by = s8 % gy;

    const __bf16* gA = p.A + (long)bx * 256 * p.lda;
    const __bf16* gB = p.B + (long)by * 256 * p.ldb;

    // staging: thread covers rows rS/rS+128, 16B at colbyte ctb (XOR-preswizzled source)
    const int rS = tid >> 2;
    const int ctb = (tid & 3) * 16;
    const int scol = (ctb ^ ((rS & 3) << 4)) >> 1;      // bf16 elems within 32-col row

    unsigned lbase = (unsigned)(unsigned long long)(__attribute__((address_space(3))) char*)&smem[0];
    const unsigned swr = ((unsigned)(kg << 4)) ^ ((unsigned)((lr & 3) << 4));
    const unsigned aoffL = (unsigned)((wr + lr) * 64) + swr;
    const unsigned boffL = (unsigned)((wc + lr) * 64) + swr + 16384u;

    f32x4 acc[8][4] = {};
    bf16x8 bA[4], bA2[4], bB[4];

    auto STAGE = [&](int op, int st, int slot) {
        const __bf16* gp = op ? gB : gA;
        int ld = op ? p.ldb : p.lda;
        const __bf16* s0 = gp + (long)rS * ld + (long)st * 32 + scol;
        const char* d = smem + slot * 32768 + op * 16384 + (wave << 10);
        gload16(s0, d);
        gload16(s0 + (long)128 * ld, d + 8192);
    };

    // prologue: tile0 -> slot0, tile1 -> slot1 (8 gloads); wait tile0 (vmcnt(4))
    {
        int t1 = (p.nT > 1) ? 1 : 0;
        STAGE(0, 0, 0); STAGE(1, 0, 0);
        STAGE(0, t1, 1); STAGE(1, t1, 1);
    }
    asm volatile("s_waitcnt vmcnt(4)" ::: "memory");
    __builtin_amdgcn_s_barrier();

    const int nT = p.nT;
    for (int t = 0; t < nT; ++t) {
        const int db = t & 1;
        const int t2 = (t + 2 < nT) ? t + 2 : nT - 1;
        const unsigned sb = (unsigned)(db * 32768);
        // 12 ds_reads: A mb0-3, B 0-3, A mb4-7
#pragma unroll
        for (int i = 0; i < 4; ++i) bA[i]  = ds_read16(lbase + sb + aoffL + i * 1024);
#pragma unroll
        for (int i = 0; i < 4; ++i) bB[i]  = ds_read16(lbase + sb + boffL + i * 1024);
#pragma unroll
        for (int i = 0; i < 4; ++i) bA2[i] = ds_read16(lbase + sb + aoffL + (4 + i) * 1024);
        asm volatile("s_waitcnt lgkmcnt(4)" ::: "memory");   // first 8 (bA,bB) done
        __builtin_amdgcn_sched_barrier(0);
        __builtin_amdgcn_s_setprio(1);
#pragma unroll
        for (int i = 0; i < 4; ++i)
#pragma unroll
            for (int j = 0; j < 4; ++j)
                acc[i][j] = __builtin_amdgcn_mfma_f32_16x16x32_bf16(bA[i], bB[j], acc[i][j], 0, 0, 0);
        __builtin_amdgcn_s_setprio(0);
        asm volatile("s_waitcnt lgkmcnt(0)" ::: "memory");   // bA2 done; all reads of slot db done
        __builtin_amdgcn_sched_barrier(0);
        __builtin_amdgcn_s_barrier();                        // every wave done reading slot db
        STAGE(0, t2, db); STAGE(1, t2, db);                  // overwrite slot db with tile t+2
        __builtin_amdgcn_s_setprio(1);
#pragma unroll
        for (int i = 0; i < 4; ++i)
#pragma unroll
            for (int j = 0; j < 4; ++j)
                acc[4 + i][j] = __builtin_amdgcn_mfma_f32_16x16x32_bf16(bA2[i], bB[j], acc[4 + i][j], 0, 0, 0);
        __builtin_amdgcn_s_setprio(0);
        asm volatile("s_waitcnt vmcnt(4)" ::: "memory");     // tile t+1 (slot db^1) landed
        __builtin_amdgcn_s_barrier();
    }
    asm volatile("s_waitcnt vmcnt(0)" ::: "memory");         // drain tail DMA before exit
    __builtin_amdgcn_s_barrier();

    // epilogue
#pragma unroll
    for (int mi = 0; mi < 8; ++mi) {
#pragma unroll
        for (int nj = 0; nj < 4; ++nj) {
            int row0 = bx*256 + wr + mi*16 + kg*4;
            int col  = by*256 + wc + nj*16 + lr;
            if constexpr (EPI == 0) {
                if (col < 2048) {
                    bf16x4 vv;
                    #pragma unroll
                    for (int q = 0; q < 4; q++) vv[q] = (__bf16)silu_f(acc[mi][nj][q] + p.c0[col]);
                    *(bf16x4*)(p.o0 + (long)col*16384 + row0) = vv;     // vT[e][t]
                } else {
                    #pragma unroll
                    for (int q = 0; q < 4; q++)
                        p.o1[(long)(row0+q)*2048 + (col - 2048)] = (__bf16)silu_f(acc[mi][nj][q] + p.c0[col]);
                }
            } else {   // EPI == 6
                #pragma unroll
                for (int q = 0; q < 4; q++) {
                    long idx = (long)(row0+q)*1024 + col;
                    p.outF[idx] = acc[mi][nj][q] + p.c0[col] + p.c1[idx];
                }
            }
        }
    }
}

// ---------------- generic 128^2 MFMA GEMM (2-phase, gload_lds) ----------------
struct GP {
    const __bf16* A;
    const __bf16* B;
    const __bf16* A2;
    const __bf16* B2;
    int lda, ldb, kSteps;
    long sAz, sBz, sCz;
    float scale;
    float* outF;
    __bf16 *o0, *o1, *o2, *o3;
    const float *c0, *c1, *c2;
    __bf16* gbuf;
};

// EPI: 1=QK(silu+4 heads) 2=SIM(/256+bias, relu^2) 4=LINKV partial(scaled, transposed store)
//      6=FINAL(+b_o+x, fp32)
template<int EPI>
__global__ __launch_bounds__(256, 2) void gemm_kernel(GP p) {
    __shared__ __bf16 As[128*32];
    __shared__ __bf16 Bs[128*32];
    int z = blockIdx.z;
    const __bf16* A = p.A + (long)z * p.sAz + (long)blockIdx.x * 128 * p.lda;
    const __bf16* B = p.B + (long)z * p.sBz + (long)blockIdx.y * 128 * p.ldb;
    int tid = threadIdx.x;
    int wave = tid >> 6, lane = tid & 63;
    int wr = (wave >> 1) * 64, wc = (wave & 1) * 64;
    int lr = lane & 15, kg = lane >> 4;

    f32x4 acc[4][4] = {};

    int lsub = lane >> 2;
    int scol = (lane & 3) * 8;
    const __bf16* Ag = A + scol + (long)(wave*32 + lsub) * p.lda;
    const __bf16* Bg = B + scol + (long)(wave*32 + lsub) * p.ldb;
    long a16 = (long)16 * p.lda, b16 = (long)16 * p.ldb;
    __bf16* AsW = As + wave * 32 * 32;
    __bf16* BsW = Bs + wave * 32 * 32;

    for (int ks = 0; ks < p.kSteps; ++ks) {
        long k0 = (long)ks * 32;
        __syncthreads();
        gload16(Ag + k0,       (const char*)AsW);
        gload16(Ag + k0 + a16, (const char*)(AsW + 16*32));
        gload16(Bg + k0,       (const char*)BsW);
        gload16(Bg + k0 + b16, (const char*)(BsW + 16*32));
        __syncthreads();
        bf16x8 af[4], bfr[4];
        #pragma unroll
        for (int i = 0; i < 4; i++) af[i]  = *(const bf16x8*)(As + (wr + i*16 + lr)*32 + kg*8);
        #pragma unroll
        for (int i = 0; i < 4; i++) bfr[i] = *(const bf16x8*)(Bs + (wc + i*16 + lr)*32 + kg*8);
        #pragma unroll
        for (int i = 0; i < 4; i++)
            #pragma unroll
            for (int j = 0; j < 4; j++)
                acc[i][j] = __builtin_amdgcn_mfma_f32_16x16x32_bf16(af[i], bfr[j], acc[i][j], 0, 0, 0);
    }

    int bx = blockIdx.x, by = blockIdx.y;
    #pragma unroll
    for (int i = 0; i < 4; i++) {
        #pragma unroll
        for (int j = 0; j < 4; j++) {
            int row0 = bx*128 + wr + i*16 + kg*4;
            int col  = by*128 + wc + j*16 + lr;
            if constexpr (EPI == 1) {
                float sv[4];
                #pragma unroll
                for (int q = 0; q < 4; q++) sv[q] = silu_f(acc[i][j][q] + p.c0[col]);
                #pragma unroll
                for (int q = 0; q < 4; q++) {
                    p.o0[(long)(row0+q)*128 + col] = (__bf16)(sv[q] * p.c1[      col] + p.c2[      col]);
                    p.o1[(long)(row0+q)*128 + col] = (__bf16)(sv[q] * p.c1[256 + col] + p.c2[256 + col]);
                    p.o2[(long)(row0+q)*128 + col] = (__bf16)(sv[q] * p.c1[128 + col] + p.c2[128 + col]);
                }
                bf16x4 lk;
                #pragma unroll
                for (int q = 0; q < 4; q++) lk[q] = (__bf16)(sv[q] * p.c1[384 + col] + p.c2[384 + col]);
                *(bf16x4*)(p.o3 + (long)col*16384 + row0) = lk;
            } else if constexpr (EPI == 2) {
                #pragma unroll
                for (int q = 0; q < 4; q++) {
                    int row = row0 + q;
                    float s = acc[i][j][q] * (1.0f/256.0f) + p.c0[row*256 + col];
                    s = fmaxf(s, 0.0f);
                    p.o0[(long)z*p.sCz + (long)row*256 + col] = (__bf16)(s * s);
                }
            } else if constexpr (EPI == 4) {
                bf16x4 vv;
                #pragma unroll
                for (int q = 0; q < 4; q++) vv[q] = (__bf16)(acc[i][j][q] * p.scale);
                *(bf16x4*)(p.o0 + (long)z*p.sCz + (long)col*128 + row0) = vv;
            } else if constexpr (EPI == 6) {
                #pragma unroll
                for (int q = 0; q < 4; q++) {
                    long idx = (long)(row0+q)*1024 + col;
                    p.outF[idx] = acc[i][j][q] + p.c0[col] + p.c1[idx];
                }
            }
        }
    }
}

// ---------------- fused quad_out + lin_out + gate (in-place into gate buffer) ----------------
__global__ __launch_bounds__(256, 2) void quadlin_kernel(GP p) {
    __shared__ __bf16 As[128*32];
    __shared__ __bf16 Bs[128*32];
    int z = blockIdx.z;
    int batch = z >> 4;
    int tid = threadIdx.x;
    int wave = tid >> 6, lane = tid & 63;
    int wr = (wave >> 1) * 64, wc = (wave & 1) * 64;
    int lr = lane & 15, kg = lane >> 4;
    int lsub = lane >> 2;
    int scol = (lane & 3) * 8;
    __bf16* AsW = As + wave * 32 * 32;
    __bf16* BsW = Bs + wave * 32 * 32;

    f32x4 acc[4][4] = {};

    {
        const __bf16* Ag = p.A + (long)z * 65536 + (long)blockIdx.x * 128 * 256
                         + scol + (long)(wave*32 + lsub) * 256;
        const __bf16* Bg = p.B + (long)z * 256 + (long)blockIdx.y * 128 * 16384
                         + scol + (long)(wave*32 + lsub) * 16384;
        for (int ks = 0; ks < 8; ++ks) {
            long k0 = (long)ks * 32;
            __syncthreads();
            gload16(Ag + k0,             (const char*)AsW);
            gload16(Ag + k0 + 16*256,    (const char*)(AsW + 16*32));
            gload16(Bg + k0,             (const char*)BsW);
            gload16(Bg + k0 + 16L*16384, (const char*)(BsW + 16*32));
            __syncthreads();
            bf16x8 af[4], bfr[4];
            #pragma unroll
            for (int i = 0; i < 4; i++) af[i]  = *(const bf16x8*)(As + (wr + i*16 + lr)*32 + kg*8);
            #pragma unroll
            for (int i = 0; i < 4; i++) bfr[i] = *(const bf16x8*)(Bs + (wc + i*16 + lr)*32 + kg*8);
            #pragma unroll
            for (int i = 0; i < 4; i++)
                #pragma unroll
                for (int j = 0; j < 4; j++)
                    acc[i][j] = __builtin_amdgcn_mfma_f32_16x16x32_bf16(af[i], bfr[j], acc[i][j], 0, 0, 0);
        }
    }
    {
        const __bf16* Ag = p.A2 + ((long)z * 256 + (long)blockIdx.x * 128) * 128
                         + scol + (long)(wave*32 + lsub) * 128;
        const __bf16* Bg = p.B2 + (long)batch * 2048 * 128 + (long)blockIdx.y * 128 * 128
                         + scol + (long)(wave*32 + lsub) * 128;
        for (int ks = 0; ks < 4; ++ks) {
            long k0 = (long)ks * 32;
            __syncthreads();
            gload16(Ag + k0,          (const char*)AsW);
            gload16(Ag + k0 + 16*128, (const char*)(AsW + 16*32));
            gload16(Bg + k0,          (const char*)BsW);
            gload16(Bg + k0 + 16*128, (const char*)(BsW + 16*32));
            __syncthreads();
            bf16x8 af[4], bfr[4];
            #pragma unroll
            for (int i = 0; i < 4; i++) af[i]  = *(const bf16x8*)(As + (wr + i*16 + lr)*32 + kg*8);
            #pragma unroll
            for (int i = 0; i < 4; i++) bfr[i] = *(const bf16x8*)(Bs + (wc + i*16 + lr)*32 + kg*8);
            #pragma unroll
            for (int i = 0; i < 4; i++)
                #pragma unroll
                for (int j = 0; j < 4; j++)
                    acc[i][j] = __builtin_amdgcn_mfma_f32_16x16x32_bf16(af[i], bfr[j], acc[i][j], 0, 0, 0);
        }
    }
    #pragma unroll
    for (int i = 0; i < 4; i++) {
        #pragma unroll
        for (int j = 0; j < 4; j++) {
            int row0 = z*256 + blockIdx.x*128 + wr + i*16 + kg*4;
            int col  = blockIdx.y*128 + wc + j*16 + lr;
            #pragma unroll
            for (int q = 0; q < 4; q++) {
                long idx = (long)(row0+q)*2048 + col;
                float g = (float)p.gbuf[idx];
                p.gbuf[idx] = (__bf16)(g * acc[i][j][q]);
            }
        }
    }
}

extern "C" void kernel_launch(void* const* d_in, const int* in_sizes, int n_in,
                              void* d_out, int out_size, void* d_ws, size_t ws_size,
                              hipStream_t stream) {
    const float* x       = (const float*)d_in[0];
    const float* ln_g    = (const float*)d_in[1];
    const float* ln_b    = (const float*)d_in[2];
    const float* W_h     = (const float*)d_in[3];
    const float* b_h     = (const float*)d_in[4];
    const float* W_qk    = (const float*)d_in[5];
    const float* b_qk    = (const float*)d_in[6];
    const float* os_g    = (const float*)d_in[7];
    const float* os_b    = (const float*)d_in[8];
    const float* rel_emb = (const float*)d_in[9];
    const float* W_o     = (const float*)d_in[10];
    const float* b_o     = (const float*)d_in[11];
    float* out = (float*)d_out;

    const size_t MB = 1024 * 1024;
    if (ws_size < 190 * MB) return;

    char* ws = (char*)d_ws;
    __bf16* gate = (__bf16*)(ws + 0);          // 64 MB
    __bf16* vT   = (__bf16*)(ws + 64*MB);      // 64 MB
    __bf16* norm = (__bf16*)(ws + 128*MB);     // 32 MB (dead after gemm<1>)
    __bf16* attn = (__bf16*)(ws + 128*MB);     //  8 MB (aliases norm)
    __bf16* lkvT = (__bf16*)(ws + 136*MB);     //  2 MB (aliases norm)
    __bf16* lkvP = (__bf16*)(ws + 140*MB);     // 16 MB split-K partials (aliases norm)
    __bf16* qq   = (__bf16*)(ws + 160*MB);
    __bf16* qk2  = (__bf16*)(ws + 164*MB);
    __bf16* lq   = (__bf16*)(ws + 168*MB);
    __bf16* lkT  = (__bf16*)(ws + 172*MB);
    float*  bmat = (float* )(ws + 176*MB);
    __bf16* WqkT = (__bf16*)(ws + 176*MB + 256*1024);
    __bf16* WoT  = (__bf16*)(ws + 177*MB);
    __bf16* WhT  = (__bf16*)(ws + 181*MB);

    relbias_kernel<<<256, 256, 0, stream>>>(rel_emb, bmat);
    ln_kernel<<<16384, 256, 0, stream>>>(x, ln_g, ln_b, norm);
    dim3 tb(32, 8);
    transpose_kernel<<<dim3(128, 32), tb, 0, stream>>>(W_h,  WhT,  1024, 4096);
    transpose_kernel<<<dim3(4,   32), tb, 0, stream>>>(W_qk, WqkT, 1024, 128);
    transpose_kernel<<<dim3(32,  64), tb, 0, stream>>>(W_o,  WoT,  2048, 1024);

    // hidden = silu(norm @ W_h + b_h): v -> vT (e-major), gate token-major  [256^2 v2, 2 blk/CU]
    {
        G2 p{}; p.A = norm; p.B = WhT; p.lda = 1024; p.ldb = 1024; p.nT = 32;
        p.c0 = b_h; p.o0 = vT; p.o1 = gate;
        gemm256v2<0><<<dim3(64, 16), 512, 0, stream>>>(p);
    }
    // qk = silu(norm @ W_qk + b_qk) -> quad_q, quad_k, lin_q, lin_k^T
    {
        GP p{}; p.A = norm; p.B = WqkT; p.lda = 1024; p.ldb = 1024; p.kSteps = 32;
        p.c0 = b_qk; p.c1 = os_g; p.c2 = os_b;
        p.o0 = qq; p.o1 = qk2; p.o2 = lq; p.o3 = lkT;
        gemm_kernel<1><<<dim3(128, 1, 1), 256, 0, stream>>>(p);
    }
    // attn = relu(qq @ qk^T / 256 + bias)^2   per group
    {
        GP p{}; p.A = qq; p.B = qk2; p.lda = 128; p.ldb = 128; p.kSteps = 4;
        p.sAz = 256*128; p.sBz = 256*128; p.sCz = 256*256;
        p.c0 = bmat; p.o0 = attn;
        gemm_kernel<2><<<dim3(2, 2, 64), 256, 0, stream>>>(p);
    }
    // lin_kv split-K: z = batch*8 + chunk (K=512 each); partials -> lkvP[z][e][d]
    {
        GP p{}; p.A = lkT; p.B = vT; p.lda = 16384; p.ldb = 16384; p.kSteps = 16;
        p.sAz = 512; p.sBz = 512; p.sCz = 2048*128; p.scale = 1.0f/4096.0f;
        p.o0 = lkvP;
        gemm_kernel<4><<<dim3(1, 16, 32), 256, 0, stream>>>(p);
    }
    reduce8_kernel<<<1024, 256, 0, stream>>>(lkvP, lkvT);
    // gate <- gate * (attn @ v + lin_q @ lin_kv)
    {
        GP p{}; p.A = attn; p.B = vT; p.A2 = lq; p.B2 = lkvT; p.gbuf = gate;
        quadlin_kernel<<<dim3(2, 16, 64), 256, 0, stream>>>(p);
    }
    // final = combined @ W_o + b_o + x   [128^2 2-phase]
    {
        GP p{}; p.A = gate; p.B = WoT; p.lda = 2048; p.ldb = 2048; p.kSteps = 64;
        p.c0 = b_o; p.c1 = x; p.outF = out;
        gemm_kernel<6><<<dim3(128, 8, 1), 256, 0, stream>>>(p);
    }
}

// Round 10
// 475.354 us; speedup vs baseline: 3.3844x; 3.3844x over previous
//
#include <hip/hip_runtime.h>
#include <hip/hip_bf16.h>

typedef float  f32x4  __attribute__((ext_vector_type(4)));
typedef __bf16 bf16x8 __attribute__((ext_vector_type(8)));
typedef __bf16 bf16x4 __attribute__((ext_vector_type(4)));

__device__ __forceinline__ float silu_f(float x) { return x / (1.0f + __expf(-x)); }

__device__ __forceinline__ void gload16(const __bf16* g, const char* lds) {
    __builtin_amdgcn_global_load_lds((const __attribute__((address_space(1))) void*)g,
                                     (__attribute__((address_space(3))) void*)lds, 16, 0, 0);
}

__device__ __forceinline__ bf16x8 ds_read16(unsigned addr) {
    bf16x8 d;
    asm volatile("ds_read_b128 %0, %1" : "=v"(d) : "v"(addr));
    return d;
}

template<int IMB>
__device__ __forceinline__ void mfma16(f32x4 (&acc)[8][4], bf16x8 (&bA)[4], bf16x8 (&bB)[4]) {
#pragma unroll
    for (int im = 0; im < 4; ++im)
#pragma unroll
        for (int nj = 0; nj < 4; ++nj)
            acc[IMB + im][nj] = __builtin_amdgcn_mfma_f32_16x16x32_bf16(bA[im], bB[nj], acc[IMB + im][nj], 0, 0, 0);
}

// ---------------- LayerNorm -> bf16 ----------------
__global__ __launch_bounds__(256) void ln_kernel(const float* __restrict__ x,
                                                 const float* __restrict__ g,
                                                 const float* __restrict__ b,
                                                 __bf16* __restrict__ out) {
    int row = blockIdx.x;
    const float* xr = x + (long)row * 1024;
    int t = threadIdx.x;
    f32x4 v = *(const f32x4*)(xr + t * 4);
    float s  = v[0] + v[1] + v[2] + v[3];
    float ss = v[0]*v[0] + v[1]*v[1] + v[2]*v[2] + v[3]*v[3];
    #pragma unroll
    for (int off = 32; off > 0; off >>= 1) {
        s  += __shfl_down(s, off);
        ss += __shfl_down(ss, off);
    }
    __shared__ float red[8];
    int wave = t >> 6, lane = t & 63;
    if (lane == 0) { red[wave*2] = s; red[wave*2+1] = ss; }
    __syncthreads();
    float S  = red[0] + red[2] + red[4] + red[6];
    float SS = red[1] + red[3] + red[5] + red[7];
    float mean = S * (1.0f/1024.0f);
    float var  = SS * (1.0f/1024.0f) - mean*mean;
    float rstd = rsqrtf(var + 1e-5f);
    __bf16* orow = out + (long)row * 1024;
    #pragma unroll
    for (int j = 0; j < 4; j++) {
        float fv = (v[j] - mean) * rstd * g[t*4+j] + b[t*4+j];
        orow[t*4+j] = (__bf16)fv;
    }
}

// ---------------- T5 relative bias matrix (256x256, fp32) ----------------
__global__ __launch_bounds__(256) void relbias_kernel(const float* __restrict__ rel_emb,
                                                      float* __restrict__ bmat) {
    int idx = blockIdx.x * 256 + threadIdx.x;
    int i = idx >> 8, j = idx & 255;
    int n = i - j;
    int ret = (n < 0) ? 16 : 0;
    int an = (n < 0) ? -n : n;
    int bucket;
    if (an < 8) {
        bucket = ret + an;
    } else {
        float vl = logf((float)an * 0.125f) / 2.772588722239781f * 8.0f;
        int lv = 8 + (int)vl;
        bucket = ret + (lv < 15 ? lv : 15);
    }
    bmat[idx] = rel_emb[bucket] * 11.313708498984761f;
}

// ---------------- transpose (rows x cols) fp32 -> bf16 (cols x rows) ----------------
__global__ __launch_bounds__(256) void transpose_kernel(const float* __restrict__ in,
                                                        __bf16* __restrict__ out,
                                                        int rows, int cols) {
    __shared__ __bf16 tile[32][33];
    int c0 = blockIdx.x * 32, r0 = blockIdx.y * 32;
    int lx = threadIdx.x, ly = threadIdx.y;
    #pragma unroll
    for (int i = 0; i < 4; i++) {
        int r = ly + i*8;
        tile[r][lx] = (__bf16)in[(long)(r0 + r) * cols + c0 + lx];
    }
    __syncthreads();
    #pragma unroll
    for (int i = 0; i < 4; i++) {
        int c = ly + i*8;
        out[(long)(c0 + c) * rows + r0 + lx] = tile[lx][c];
    }
}

// ---------------- reduce 8 bf16 partials -> bf16 ----------------
__global__ __launch_bounds__(256) void reduce8_kernel(const __bf16* __restrict__ in,
                                                      __bf16* __restrict__ out) {
    int i = (blockIdx.x * 256 + threadIdx.x) * 4;
    int b = i >> 18;
    int r = i & 262143;
    float s0 = 0.f, s1 = 0.f, s2 = 0.f, s3 = 0.f;
    #pragma unroll
    for (int c = 0; c < 8; ++c) {
        bf16x4 v = *(const bf16x4*)(in + ((long)(b*8 + c) << 18) + r);
        s0 += (float)v[0]; s1 += (float)v[1]; s2 += (float)v[2]; s3 += (float)v[3];
    }
    bf16x4 o; o[0] = (__bf16)s0; o[1] = (__bf16)s1; o[2] = (__bf16)s2; o[3] = (__bf16)s3;
    *(bf16x4*)(out + i) = o;
}

// ================= 256x256 8-phase GEMM (r4 schedule + CORRECTED swizzle) =========
// C[m][n] = sum_k A[m][k]*B[n][k]; A: MxK row-major, B: NxK row-major, K = nT*64.
// 8 waves (2Mx4N), per-wave 128x64 (8x4 frags of 16x16x32). LDS 128KB: 2 K-tile slots,
// each [A|B][kh][256 rows][64B]. Swizzle: 16B col-slot ^= (row>>2)&3 (involution;
// reader's quarter-wave hits all 8 bank-quads exactly 2x -> conflict-free; the old
// (row&3) variant left rows differing by 4 on the same quad -> 4-way).
struct G2 {
    const __bf16 *A, *B;
    int lda, ldb, nT;
    float* outF;
    __bf16 *o0, *o1;
    const float *c0, *c1;
};

template<int EPI>
__global__ __launch_bounds__(512, 2) void gemm256(G2 p) {
    __shared__ __align__(128) char smem[131072];
    const int tid = threadIdx.x;
    const int wave = tid >> 6, lane = tid & 63;
    const int wr = (wave >> 2) * 128, wc = (wave & 3) * 64;
    const int lr = lane & 15, kg = lane >> 4;

    // XCD-bijective swizzle (nwg % 8 == 0)
    const int gx = gridDim.x, gy = gridDim.y;
    int f = blockIdx.y * gx + blockIdx.x;
    int cpx = (gx * gy) >> 3;
    int s8 = (f & 7) * cpx + (f >> 3);
    int bx = s8 / gy, by = s8 % gy;

    const __bf16* gA = p.A + (long)bx * 256 * p.lda;
    const __bf16* gB = p.B + (long)by * 256 * p.ldb;

    const int rS = tid >> 2;
    const int ctb = (tid & 3) * 16;
    const int scol = (ctb ^ (((rS >> 2) & 3) << 4)) >> 1;   // corrected: row bits 2-3

    unsigned lbase = (unsigned)(unsigned long long)(__attribute__((address_space(3))) char*)&smem[0];
    const unsigned swr = ((unsigned)(kg << 4)) ^ ((unsigned)(((lr >> 2) & 3) << 4));  // corrected
    const unsigned aoffL = (unsigned)((wr + lr) * 64) + swr;
    const unsigned boffL = (unsigned)((wc + lr) * 64) + swr;

    f32x4 acc[8][4] = {};
    bf16x8 bA[4], bB[4];

    auto STAGE = [&](int op, int kh, int st, int slot) {
        const __bf16* gp = op ? gB : gA;
        int ld = op ? p.ldb : p.lda;
        const __bf16* s0 = gp + (long)rS * ld + (long)st * 64 + kh * 32 + scol;
        const char* d = smem + slot * 65536 + op * 32768 + kh * 16384 + (wave << 10);
        gload16(s0, d);
        gload16(s0 + (long)128 * ld, d + 8192);
    };
    auto LDA4 = [&](int slot, int kk, int mb) {
#pragma unroll
        for (int i = 0; i < 4; ++i)
            bA[i] = ds_read16(lbase + slot * 65536 + kk * 16384 + aoffL + (mb + i) * 1024);
    };
    auto LDB4 = [&](int slot, int kk) {
#pragma unroll
        for (int i = 0; i < 4; ++i)
            bB[i] = ds_read16(lbase + slot * 65536 + 32768 + kk * 16384 + boffL + i * 1024);
    };

    // prologue: tile0 kh0+kh1, tile1 kh0
    STAGE(0, 0, 0, 0); STAGE(1, 0, 0, 0);
    STAGE(0, 1, 0, 0); STAGE(1, 1, 0, 0);
    {
        int t1 = (p.nT > 1) ? 1 : 0;
        STAGE(0, 0, t1, 1); STAGE(1, 0, t1, 1);
    }
    asm volatile("s_waitcnt vmcnt(8)" ::: "memory");
    __builtin_amdgcn_s_barrier();

    for (int s = 0; s < p.nT; ++s) {
        const int db = s & 1;
        const int t1 = (s + 1 < p.nT) ? s + 1 : p.nT - 1;
        const int t2 = (s + 2 < p.nT) ? s + 2 : p.nT - 1;
        const int p1 = (s + 1) & 1;
        // ---- PH0: kk=0, mi 0-3 ----
        LDA4(db, 0, 0); LDB4(db, 0);
        STAGE(0, 1, t1, p1);
        __builtin_amdgcn_s_barrier();
        asm volatile("s_waitcnt lgkmcnt(0)" ::: "memory");
        __builtin_amdgcn_sched_barrier(0);
        __builtin_amdgcn_s_setprio(1);
        mfma16<0>(acc, bA, bB);
        __builtin_amdgcn_s_setprio(0);
        __builtin_amdgcn_s_barrier();
        // ---- PH1: kk=0, mi 4-7 ----
        LDA4(db, 0, 4);
        STAGE(1, 1, t1, p1);
        __builtin_amdgcn_s_barrier();
        asm volatile("s_waitcnt lgkmcnt(0)" ::: "memory");
        __builtin_amdgcn_sched_barrier(0);
        __builtin_amdgcn_s_setprio(1);
        mfma16<4>(acc, bA, bB);
        __builtin_amdgcn_s_setprio(0);
        asm volatile("s_waitcnt vmcnt(8)" ::: "memory");
        __builtin_amdgcn_s_barrier();
        // ---- PH2: kk=1, mi 0-3 ----
        LDA4(db, 1, 0); LDB4(db, 1);
        STAGE(0, 0, t2, db);
        __builtin_amdgcn_s_barrier();
        asm volatile("s_waitcnt lgkmcnt(0)" ::: "memory");
        __builtin_amdgcn_sched_barrier(0);
        __builtin_amdgcn_s_setprio(1);
        mfma16<0>(acc, bA, bB);
        __builtin_amdgcn_s_setprio(0);
        __builtin_amdgcn_s_barrier();
        // ---- PH3: kk=1, mi 4-7 ----
        LDA4(db, 1, 4);
        STAGE(1, 0, t2, db);
        __builtin_amdgcn_s_barrier();
        asm volatile("s_waitcnt lgkmcnt(0)" ::: "memory");
        __builtin_amdgcn_sched_barrier(0);
        __builtin_amdgcn_s_setprio(1);
        mfma16<4>(acc, bA, bB);
        __builtin_amdgcn_s_setprio(0);
        asm volatile("s_waitcnt vmcnt(8)" ::: "memory");
        __builtin_amdgcn_s_barrier();
    }
    asm volatile("s_waitcnt vmcnt(0)" ::: "memory");
    __builtin_amdgcn_s_barrier();

    // epilogue
#pragma unroll
    for (int mi = 0; mi < 8; ++mi) {
#pragma unroll
        for (int nj = 0; nj < 4; ++nj) {
            int row0 = bx*256 + wr + mi*16 + kg*4;
            int col  = by*256 + wc + nj*16 + lr;
            if constexpr (EPI == 0) {
                if (col < 2048) {
                    bf16x4 vv;
                    #pragma unroll
                    for (int q = 0; q < 4; q++) vv[q] = (__bf16)silu_f(acc[mi][nj][q] + p.c0[col]);
                    *(bf16x4*)(p.o0 + (long)col*16384 + row0) = vv;     // vT[e][t]
                } else {
                    #pragma unroll
                    for (int q = 0; q < 4; q++)
                        p.o1[(long)(row0+q)*2048 + (col - 2048)] = (__bf16)silu_f(acc[mi][nj][q] + p.c0[col]);
                }
            } else {   // EPI == 6 (unused this round)
                #pragma unroll
                for (int q = 0; q < 4; q++) {
                    long idx = (long)(row0+q)*1024 + col;
                    p.outF[idx] = acc[mi][nj][q] + p.c0[col] + p.c1[idx];
                }
            }
        }
    }
}

// ---------------- generic 128^2 MFMA GEMM (2-phase, gload_lds) ----------------
struct GP {
    const __bf16* A;
    const __bf16* B;
    const __bf16* A2;
    const __bf16* B2;
    int lda, ldb, kSteps;
    long sAz, sBz, sCz;
    float scale;
    float* outF;
    __bf16 *o0, *o1, *o2, *o3;
    const float *c0, *c1, *c2;
    __bf16* gbuf;
};

// EPI: 1=QK(silu+4 heads) 2=SIM(/256+bias, relu^2) 4=LINKV partial(scaled, transposed store)
//      6=FINAL(+b_o+x, fp32)
template<int EPI>
__global__ __launch_bounds__(256, 2) void gemm_kernel(GP p) {
    __shared__ __bf16 As[128*32];
    __shared__ __bf16 Bs[128*32];
    int z = blockIdx.z;
    const __bf16* A = p.A + (long)z * p.sAz + (long)blockIdx.x * 128 * p.lda;
    const __bf16* B = p.B + (long)z * p.sBz + (long)blockIdx.y * 128 * p.ldb;
    int tid = threadIdx.x;
    int wave = tid >> 6, lane = tid & 63;
    int wr = (wave >> 1) * 64, wc = (wave & 1) * 64;
    int lr = lane & 15, kg = lane >> 4;

    f32x4 acc[4][4] = {};

    int lsub = lane >> 2;
    int scol = (lane & 3) * 8;
    const __bf16* Ag = A + scol + (long)(wave*32 + lsub) * p.lda;
    const __bf16* Bg = B + scol + (long)(wave*32 + lsub) * p.ldb;
    long a16 = (long)16 * p.lda, b16 = (long)16 * p.ldb;
    __bf16* AsW = As + wave * 32 * 32;
    __bf16* BsW = Bs + wave * 32 * 32;

    for (int ks = 0; ks < p.kSteps; ++ks) {
        long k0 = (long)ks * 32;
        __syncthreads();
        gload16(Ag + k0,       (const char*)AsW);
        gload16(Ag + k0 + a16, (const char*)(AsW + 16*32));
        gload16(Bg + k0,       (const char*)BsW);
        gload16(Bg + k0 + b16, (const char*)(BsW + 16*32));
        __syncthreads();
        bf16x8 af[4], bfr[4];
        #pragma unroll
        for (int i = 0; i < 4; i++) af[i]  = *(const bf16x8*)(As + (wr + i*16 + lr)*32 + kg*8);
        #pragma unroll
        for (int i = 0; i < 4; i++) bfr[i] = *(const bf16x8*)(Bs + (wc + i*16 + lr)*32 + kg*8);
        #pragma unroll
        for (int i = 0; i < 4; i++)
            #pragma unroll
            for (int j = 0; j < 4; j++)
                acc[i][j] = __builtin_amdgcn_mfma_f32_16x16x32_bf16(af[i], bfr[j], acc[i][j], 0, 0, 0);
    }

    int bx = blockIdx.x, by = blockIdx.y;
    #pragma unroll
    for (int i = 0; i < 4; i++) {
        #pragma unroll
        for (int j = 0; j < 4; j++) {
            int row0 = bx*128 + wr + i*16 + kg*4;
            int col  = by*128 + wc + j*16 + lr;
            if constexpr (EPI == 1) {
                float sv[4];
                #pragma unroll
                for (int q = 0; q < 4; q++) sv[q] = silu_f(acc[i][j][q] + p.c0[col]);
                #pragma unroll
                for (int q = 0; q < 4; q++) {
                    p.o0[(long)(row0+q)*128 + col] = (__bf16)(sv[q] * p.c1[      col] + p.c2[      col]);
                    p.o1[(long)(row0+q)*128 + col] = (__bf16)(sv[q] * p.c1[256 + col] + p.c2[256 + col]);
                    p.o2[(long)(row0+q)*128 + col] = (__bf16)(sv[q] * p.c1[128 + col] + p.c2[128 + col]);
                }
                bf16x4 lk;
                #pragma unroll
                for (int q = 0; q < 4; q++) lk[q] = (__bf16)(sv[q] * p.c1[384 + col] + p.c2[384 + col]);
                *(bf16x4*)(p.o3 + (long)col*16384 + row0) = lk;
            } else if constexpr (EPI == 2) {
                #pragma unroll
                for (int q = 0; q < 4; q++) {
                    int row = row0 + q;
                    float s = acc[i][j][q] * (1.0f/256.0f) + p.c0[row*256 + col];
                    s = fmaxf(s, 0.0f);
                    p.o0[(long)z*p.sCz + (long)row*256 + col] = (__bf16)(s * s);
                }
            } else if constexpr (EPI == 4) {
                bf16x4 vv;
                #pragma unroll
                for (int q = 0; q < 4; q++) vv[q] = (__bf16)(acc[i][j][q] * p.scale);
                *(bf16x4*)(p.o0 + (long)z*p.sCz + (long)col*128 + row0) = vv;
            } else if constexpr (EPI == 6) {
                #pragma unroll
                for (int q = 0; q < 4; q++) {
                    long idx = (long)(row0+q)*1024 + col;
                    p.outF[idx] = acc[i][j][q] + p.c0[col] + p.c1[idx];
                }
            }
        }
    }
}

// ---------------- fused quad_out + lin_out + gate (in-place into gate buffer) ----------------
__global__ __launch_bounds__(256, 2) void quadlin_kernel(GP p) {
    __shared__ __bf16 As[128*32];
    __shared__ __bf16 Bs[128*32];
    int z = blockIdx.z;
    int batch = z >> 4;
    int tid = threadIdx.x;
    int wave = tid >> 6, lane = tid & 63;
    int wr = (wave >> 1) * 64, wc = (wave & 1) * 64;
    int lr = lane & 15, kg = lane >> 4;
    int lsub = lane >> 2;
    int scol = (lane & 3) * 8;
    __bf16* AsW = As + wave * 32 * 32;
    __bf16* BsW = Bs + wave * 32 * 32;

    f32x4 acc[4][4] = {};

    {
        const __bf16* Ag = p.A + (long)z * 65536 + (long)blockIdx.x * 128 * 256
                         + scol + (long)(wave*32 + lsub) * 256;
        const __bf16* Bg = p.B + (long)z * 256 + (long)blockIdx.y * 128 * 16384
                         + scol + (long)(wave*32 + lsub) * 16384;
        for (int ks = 0; ks < 8; ++ks) {
            long k0 = (long)ks * 32;
            __syncthreads();
            gload16(Ag + k0,             (const char*)AsW);
            gload16(Ag + k0 + 16*256,    (const char*)(AsW + 16*32));
            gload16(Bg + k0,             (const char*)BsW);
            gload16(Bg + k0 + 16L*16384, (const char*)(BsW + 16*32));
            __syncthreads();
            bf16x8 af[4], bfr[4];
            #pragma unroll
            for (int i = 0; i < 4; i++) af[i]  = *(const bf16x8*)(As + (wr + i*16 + lr)*32 + kg*8);
            #pragma unroll
            for (int i = 0; i < 4; i++) bfr[i] = *(const bf16x8*)(Bs + (wc + i*16 + lr)*32 + kg*8);
            #pragma unroll
            for (int i = 0; i < 4; i++)
                #pragma unroll
                for (int j = 0; j < 4; j++)
                    acc[i][j] = __builtin_amdgcn_mfma_f32_16x16x32_bf16(af[i], bfr[j], acc[i][j], 0, 0, 0);
        }
    }
    {
        const __bf16* Ag = p.A2 + ((long)z * 256 + (long)blockIdx.x * 128) * 128
                         + scol + (long)(wave*32 + lsub) * 128;
        const __bf16* Bg = p.B2 + (long)batch * 2048 * 128 + (long)blockIdx.y * 128 * 128
                         + scol + (long)(wave*32 + lsub) * 128;
        for (int ks = 0; ks < 4; ++ks) {
            long k0 = (long)ks * 32;
            __syncthreads();
            gload16(Ag + k0,          (const char*)AsW);
            gload16(Ag + k0 + 16*128, (const char*)(AsW + 16*32));
            gload16(Bg + k0,          (const char*)BsW);
            gload16(Bg + k0 + 16*128, (const char*)(BsW + 16*32));
            __syncthreads();
            bf16x8 af[4], bfr[4];
            #pragma unroll
            for (int i = 0; i < 4; i++) af[i]  = *(const bf16x8*)(As + (wr + i*16 + lr)*32 + kg*8);
            #pragma unroll
            for (int i = 0; i < 4; i++) bfr[i] = *(const bf16x8*)(Bs + (wc + i*16 + lr)*32 + kg*8);
            #pragma unroll
            for (int i = 0; i < 4; i++)
                #pragma unroll
                for (int j = 0; j < 4; j++)
                    acc[i][j] = __builtin_amdgcn_mfma_f32_16x16x32_bf16(af[i], bfr[j], acc[i][j], 0, 0, 0);
        }
    }
    #pragma unroll
    for (int i = 0; i < 4; i++) {
        #pragma unroll
        for (int j = 0; j < 4; j++) {
            int row0 = z*256 + blockIdx.x*128 + wr + i*16 + kg*4;
            int col  = blockIdx.y*128 + wc + j*16 + lr;
            #pragma unroll
            for (int q = 0; q < 4; q++) {
                long idx = (long)(row0+q)*2048 + col;
                float g = (float)p.gbuf[idx];
                p.gbuf[idx] = (__bf16)(g * acc[i][j][q]);
            }
        }
    }
}

extern "C" void kernel_launch(void* const* d_in, const int* in_sizes, int n_in,
                              void* d_out, int out_size, void* d_ws, size_t ws_size,
                              hipStream_t stream) {
    const float* x       = (const float*)d_in[0];
    const float* ln_g    = (const float*)d_in[1];
    const float* ln_b    = (const float*)d_in[2];
    const float* W_h     = (const float*)d_in[3];
    const float* b_h     = (const float*)d_in[4];
    const float* W_qk    = (const float*)d_in[5];
    const float* b_qk    = (const float*)d_in[6];
    const float* os_g    = (const float*)d_in[7];
    const float* os_b    = (const float*)d_in[8];
    const float* rel_emb = (const float*)d_in[9];
    const float* W_o     = (const float*)d_in[10];
    const float* b_o     = (const float*)d_in[11];
    float* out = (float*)d_out;

    const size_t MB = 1024 * 1024;
    if (ws_size < 190 * MB) return;

    char* ws = (char*)d_ws;
    __bf16* gate = (__bf16*)(ws + 0);          // 64 MB
    __bf16* vT   = (__bf16*)(ws + 64*MB);      // 64 MB
    __bf16* norm = (__bf16*)(ws + 128*MB);     // 32 MB (dead after gemm<1>)
    __bf16* attn = (__bf16*)(ws + 128*MB);     //  8 MB (aliases norm)
    __bf16* lkvT = (__bf16*)(ws + 136*MB);     //  2 MB (aliases norm)
    __bf16* lkvP = (__bf16*)(ws + 140*MB);     // 16 MB split-K partials (aliases norm)
    __bf16* qq   = (__bf16*)(ws + 160*MB);
    __bf16* qk2  = (__bf16*)(ws + 164*MB);
    __bf16* lq   = (__bf16*)(ws + 168*MB);
    __bf16* lkT  = (__bf16*)(ws + 172*MB);
    float*  bmat = (float* )(ws + 176*MB);
    __bf16* WqkT = (__bf16*)(ws + 176*MB + 256*1024);
    __bf16* WoT  = (__bf16*)(ws + 177*MB);
    __bf16* WhT  = (__bf16*)(ws + 181*MB);

    relbias_kernel<<<256, 256, 0, stream>>>(rel_emb, bmat);
    ln_kernel<<<16384, 256, 0, stream>>>(x, ln_g, ln_b, norm);
    dim3 tb(32, 8);
    transpose_kernel<<<dim3(128, 32), tb, 0, stream>>>(W_h,  WhT,  1024, 4096);
    transpose_kernel<<<dim3(4,   32), tb, 0, stream>>>(W_qk, WqkT, 1024, 128);
    transpose_kernel<<<dim3(32,  64), tb, 0, stream>>>(W_o,  WoT,  2048, 1024);

    // hidden = silu(norm @ W_h + b_h): v -> vT (e-major), gate token-major  [256^2, fixed swizzle]
    {
        G2 p{}; p.A = norm; p.B = WhT; p.lda = 1024; p.ldb = 1024; p.nT = 16;
        p.c0 = b_h; p.o0 = vT; p.o1 = gate;
        gemm256<0><<<dim3(64, 16), 512, 0, stream>>>(p);
    }
    // qk = silu(norm @ W_qk + b_qk) -> quad_q, quad_k, lin_q, lin_k^T
    {
        GP p{}; p.A = norm; p.B = WqkT; p.lda = 1024; p.ldb = 1024; p.kSteps = 32;
        p.c0 = b_qk; p.c1 = os_g; p.c2 = os_b;
        p.o0 = qq; p.o1 = qk2; p.o2 = lq; p.o3 = lkT;
        gemm_kernel<1><<<dim3(128, 1, 1), 256, 0, stream>>>(p);
    }
    // attn = relu(qq @ qk^T / 256 + bias)^2   per group
    {
        GP p{}; p.A = qq; p.B = qk2; p.lda = 128; p.ldb = 128; p.kSteps = 4;
        p.sAz = 256*128; p.sBz = 256*128; p.sCz = 256*256;
        p.c0 = bmat; p.o0 = attn;
        gemm_kernel<2><<<dim3(2, 2, 64), 256, 0, stream>>>(p);
    }
    // lin_kv split-K: z = batch*8 + chunk (K=512 each); partials -> lkvP[z][e][d]
    {
        GP p{}; p.A = lkT; p.B = vT; p.lda = 16384; p.ldb = 16384; p.kSteps = 16;
        p.sAz = 512; p.sBz = 512; p.sCz = 2048*128; p.scale = 1.0f/4096.0f;
        p.o0 = lkvP;
        gemm_kernel<4><<<dim3(1, 16, 32), 256, 0, stream>>>(p);
    }
    reduce8_kernel<<<1024, 256, 0, stream>>>(lkvP, lkvT);
    // gate <- gate * (attn @ v + lin_q @ lin_kv)
    {
        GP p{}; p.A = attn; p.B = vT; p.A2 = lq; p.B2 = lkvT; p.gbuf = gate;
        quadlin_kernel<<<dim3(2, 16, 64), 256, 0, stream>>>(p);
    }
    // final = combined @ W_o + b_o + x   [128^2 2-phase]
    {
        GP p{}; p.A = gate; p.B = WoT; p.lda = 2048; p.ldb = 2048; p.kSteps = 64;
        p.c0 = b_o; p.c1 = x; p.outF = out;
        gemm_kernel<6><<<dim3(128, 8, 1), 256, 0, stream>>>(p);
    }
}

// Round 11
// 433.603 us; speedup vs baseline: 3.7103x; 1.0963x over previous
//
#include <hip/hip_runtime.h>
#include <hip/hip_bf16.h>

typedef float  f32x4  __attribute__((ext_vector_type(4)));
typedef __bf16 bf16x8 __attribute__((ext_vector_type(8)));
typedef __bf16 bf16x4 __attribute__((ext_vector_type(4)));

__device__ __forceinline__ float silu_f(float x) { return x / (1.0f + __expf(-x)); }

__device__ __forceinline__ void gload16(const __bf16* g, const char* lds) {
    __builtin_amdgcn_global_load_lds((const __attribute__((address_space(1))) void*)g,
                                     (__attribute__((address_space(3))) void*)lds, 16, 0, 0);
}

// ---------------- LayerNorm -> bf16 ----------------
__global__ __launch_bounds__(256) void ln_kernel(const float* __restrict__ x,
                                                 const float* __restrict__ g,
                                                 const float* __restrict__ b,
                                                 __bf16* __restrict__ out) {
    int row = blockIdx.x;
    const float* xr = x + (long)row * 1024;
    int t = threadIdx.x;
    f32x4 v = *(const f32x4*)(xr + t * 4);
    float s  = v[0] + v[1] + v[2] + v[3];
    float ss = v[0]*v[0] + v[1]*v[1] + v[2]*v[2] + v[3]*v[3];
    #pragma unroll
    for (int off = 32; off > 0; off >>= 1) {
        s  += __shfl_down(s, off);
        ss += __shfl_down(ss, off);
    }
    __shared__ float red[8];
    int wave = t >> 6, lane = t & 63;
    if (lane == 0) { red[wave*2] = s; red[wave*2+1] = ss; }
    __syncthreads();
    float S  = red[0] + red[2] + red[4] + red[6];
    float SS = red[1] + red[3] + red[5] + red[7];
    float mean = S * (1.0f/1024.0f);
    float var  = SS * (1.0f/1024.0f) - mean*mean;
    float rstd = rsqrtf(var + 1e-5f);
    __bf16* orow = out + (long)row * 1024;
    #pragma unroll
    for (int j = 0; j < 4; j++) {
        float fv = (v[j] - mean) * rstd * g[t*4+j] + b[t*4+j];
        orow[t*4+j] = (__bf16)fv;
    }
}

// ---------------- merged prep: 3 weight transposes + T5 rel-bias table ----------------
// blocks [0,4096): W_h (1024x4096); [4096,4224): W_qk (1024x128);
// [4224,6272): W_o (2048x1024); [6272,6528): relbias 256x256.
__global__ __launch_bounds__(256) void prep_kernel(const float* __restrict__ W_h,
                                                   const float* __restrict__ W_qk,
                                                   const float* __restrict__ W_o,
                                                   const float* __restrict__ rel_emb,
                                                   __bf16* __restrict__ WhT,
                                                   __bf16* __restrict__ WqkT,
                                                   __bf16* __restrict__ WoT,
                                                   float* __restrict__ bmat) {
    __shared__ __bf16 tile[32][33];
    int id = blockIdx.x, tid = threadIdx.x;
    if (id >= 6272) {                       // relbias (whole block uniform)
        int idx = (id - 6272) * 256 + tid;
        int i = idx >> 8, j = idx & 255;
        int n = i - j;
        int ret = (n < 0) ? 16 : 0;
        int an = (n < 0) ? -n : n;
        int bucket;
        if (an < 8) {
            bucket = ret + an;
        } else {
            float vl = logf((float)an * 0.125f) / 2.772588722239781f * 8.0f;
            int lv = 8 + (int)vl;
            bucket = ret + (lv < 15 ? lv : 15);
        }
        bmat[idx] = rel_emb[bucket] * 11.313708498984761f;
        return;
    }
    const float* in; __bf16* outp; int rows, cols, tx, ty;
    if (id < 4096)      { in = W_h;  outp = WhT;  rows = 1024; cols = 4096; tx = id % 128; ty = id / 128; }
    else if (id < 4224) { int t = id - 4096; in = W_qk; outp = WqkT; rows = 1024; cols = 128;  tx = t % 4;  ty = t / 4; }
    else                { int t = id - 4224; in = W_o;  outp = WoT;  rows = 2048; cols = 1024; tx = t % 32; ty = t / 32; }
    int c0 = tx * 32, r0 = ty * 32;
    int lx = tid & 31, ly = tid >> 5;       // 32 x 8
    #pragma unroll
    for (int i = 0; i < 4; i++) {
        int r = ly + i*8;
        tile[r][lx] = (__bf16)in[(long)(r0 + r) * cols + c0 + lx];
    }
    __syncthreads();
    #pragma unroll
    for (int i = 0; i < 4; i++) {
        int c = ly + i*8;
        outp[(long)(c0 + c) * rows + r0 + lx] = tile[lx][c];
    }
}

// ---------------- reduce 8 bf16 partials -> bf16 ----------------
__global__ __launch_bounds__(256) void reduce8_kernel(const __bf16* __restrict__ in,
                                                      __bf16* __restrict__ out) {
    int i = (blockIdx.x * 256 + threadIdx.x) * 4;
    int b = i >> 18;
    int r = i & 262143;
    float s0 = 0.f, s1 = 0.f, s2 = 0.f, s3 = 0.f;
    #pragma unroll
    for (int c = 0; c < 8; ++c) {
        bf16x4 v = *(const bf16x4*)(in + ((long)(b*8 + c) << 18) + r);
        s0 += (float)v[0]; s1 += (float)v[1]; s2 += (float)v[2]; s3 += (float)v[3];
    }
    bf16x4 o; o[0] = (__bf16)s0; o[1] = (__bf16)s1; o[2] = (__bf16)s2; o[3] = (__bf16)s3;
    *(bf16x4*)(out + i) = o;
}

// ---------------- GP param block ----------------
struct GP {
    const __bf16* A;
    const __bf16* B;
    const __bf16* A2;
    const __bf16* B2;
    int lda, ldb, kSteps;
    long sAz, sBz, sCz;
    float scale;
    float* outF;
    __bf16 *o0, *o1, *o2, *o3;
    const float *c0, *c1, *c2;
    __bf16* gbuf;
};

// ================= 128x128 GEMM, BK=64 (2 K-halves per barrier pair) =================
// LDS = 2 x [kk][128][32] bf16 (32KB). Staging/read patterns byte-identical to the
// proven BK=32 kernel, just two K-half tiles per sync -> half the barriers per FLOP.
// EPI: 0 = H (silu; v -> vT e-major, gate token-major)   6 = FINAL (+b_o+x, fp32)
template<int EPI>
__global__ __launch_bounds__(256, 2) void gemm64_kernel(GP p) {
    __shared__ __bf16 As[2*128*32];
    __shared__ __bf16 Bs[2*128*32];
    const __bf16* A = p.A + (long)blockIdx.x * 128 * p.lda;
    const __bf16* B = p.B + (long)blockIdx.y * 128 * p.ldb;
    int tid = threadIdx.x;
    int wave = tid >> 6, lane = tid & 63;
    int wr = (wave >> 1) * 64, wc = (wave & 1) * 64;
    int lr = lane & 15, kg = lane >> 4;

    f32x4 acc[4][4] = {};

    int lsub = lane >> 2;
    int scol = (lane & 3) * 8;
    const __bf16* Ag = A + scol + (long)(wave*32 + lsub) * p.lda;
    const __bf16* Bg = B + scol + (long)(wave*32 + lsub) * p.ldb;
    long a16 = (long)16 * p.lda, b16 = (long)16 * p.ldb;
    __bf16* AsW = As + wave * 32 * 32;
    __bf16* BsW = Bs + wave * 32 * 32;

    for (int ks = 0; ks < p.kSteps; ++ks) {
        long k0 = (long)ks * 64;
        __syncthreads();
        gload16(Ag + k0,            (const char*)AsW);
        gload16(Ag + k0 + a16,      (const char*)(AsW + 16*32));
        gload16(Bg + k0,            (const char*)BsW);
        gload16(Bg + k0 + b16,      (const char*)(BsW + 16*32));
        gload16(Ag + k0 + 32,       (const char*)(AsW + 4096));
        gload16(Ag + k0 + 32 + a16, (const char*)(AsW + 4096 + 16*32));
        gload16(Bg + k0 + 32,       (const char*)(BsW + 4096));
        gload16(Bg + k0 + 32 + b16, (const char*)(BsW + 4096 + 16*32));
        __syncthreads();
#pragma unroll
        for (int kk = 0; kk < 2; ++kk) {
            bf16x8 af[4], bfr[4];
            #pragma unroll
            for (int i = 0; i < 4; i++) af[i]  = *(const bf16x8*)(As + kk*4096 + (wr + i*16 + lr)*32 + kg*8);
            #pragma unroll
            for (int i = 0; i < 4; i++) bfr[i] = *(const bf16x8*)(Bs + kk*4096 + (wc + i*16 + lr)*32 + kg*8);
            #pragma unroll
            for (int i = 0; i < 4; i++)
                #pragma unroll
                for (int j = 0; j < 4; j++)
                    acc[i][j] = __builtin_amdgcn_mfma_f32_16x16x32_bf16(af[i], bfr[j], acc[i][j], 0, 0, 0);
        }
    }

    int bx = blockIdx.x, by = blockIdx.y;
    #pragma unroll
    for (int i = 0; i < 4; i++) {
        #pragma unroll
        for (int j = 0; j < 4; j++) {
            int row0 = bx*128 + wr + i*16 + kg*4;
            int col  = by*128 + wc + j*16 + lr;
            if constexpr (EPI == 0) {
                if (col < 2048) {
                    bf16x4 vv;
                    #pragma unroll
                    for (int q = 0; q < 4; q++) vv[q] = (__bf16)silu_f(acc[i][j][q] + p.c0[col]);
                    *(bf16x4*)(p.o0 + (long)col*16384 + row0) = vv;     // vT[e][t]
                } else {
                    #pragma unroll
                    for (int q = 0; q < 4; q++)
                        p.o1[(long)(row0+q)*2048 + (col - 2048)] = (__bf16)silu_f(acc[i][j][q] + p.c0[col]);
                }
            } else {   // EPI == 6
                #pragma unroll
                for (int q = 0; q < 4; q++) {
                    long idx = (long)(row0+q)*1024 + col;
                    p.outF[idx] = acc[i][j][q] + p.c0[col] + p.c1[idx];
                }
            }
        }
    }
}

// ---------------- generic 128^2 BK=32 GEMM (gemm<1>: QK heads) ----------------
template<int EPI>
__global__ __launch_bounds__(256, 2) void gemm_kernel(GP p) {
    __shared__ __bf16 As[128*32];
    __shared__ __bf16 Bs[128*32];
    int z = blockIdx.z;
    const __bf16* A = p.A + (long)z * p.sAz + (long)blockIdx.x * 128 * p.lda;
    const __bf16* B = p.B + (long)z * p.sBz + (long)blockIdx.y * 128 * p.ldb;
    int tid = threadIdx.x;
    int wave = tid >> 6, lane = tid & 63;
    int wr = (wave >> 1) * 64, wc = (wave & 1) * 64;
    int lr = lane & 15, kg = lane >> 4;

    f32x4 acc[4][4] = {};

    int lsub = lane >> 2;
    int scol = (lane & 3) * 8;
    const __bf16* Ag = A + scol + (long)(wave*32 + lsub) * p.lda;
    const __bf16* Bg = B + scol + (long)(wave*32 + lsub) * p.ldb;
    long a16 = (long)16 * p.lda, b16 = (long)16 * p.ldb;
    __bf16* AsW = As + wave * 32 * 32;
    __bf16* BsW = Bs + wave * 32 * 32;

    for (int ks = 0; ks < p.kSteps; ++ks) {
        long k0 = (long)ks * 32;
        __syncthreads();
        gload16(Ag + k0,       (const char*)AsW);
        gload16(Ag + k0 + a16, (const char*)(AsW + 16*32));
        gload16(Bg + k0,       (const char*)BsW);
        gload16(Bg + k0 + b16, (const char*)(BsW + 16*32));
        __syncthreads();
        bf16x8 af[4], bfr[4];
        #pragma unroll
        for (int i = 0; i < 4; i++) af[i]  = *(const bf16x8*)(As + (wr + i*16 + lr)*32 + kg*8);
        #pragma unroll
        for (int i = 0; i < 4; i++) bfr[i] = *(const bf16x8*)(Bs + (wc + i*16 + lr)*32 + kg*8);
        #pragma unroll
        for (int i = 0; i < 4; i++)
            #pragma unroll
            for (int j = 0; j < 4; j++)
                acc[i][j] = __builtin_amdgcn_mfma_f32_16x16x32_bf16(af[i], bfr[j], acc[i][j], 0, 0, 0);
    }

    int bx = blockIdx.x, by = blockIdx.y;
    #pragma unroll
    for (int i = 0; i < 4; i++) {
        #pragma unroll
        for (int j = 0; j < 4; j++) {
            int row0 = bx*128 + wr + i*16 + kg*4;
            int col  = by*128 + wc + j*16 + lr;
            if constexpr (EPI == 1) {
                float sv[4];
                #pragma unroll
                for (int q = 0; q < 4; q++) sv[q] = silu_f(acc[i][j][q] + p.c0[col]);
                #pragma unroll
                for (int q = 0; q < 4; q++) {
                    p.o0[(long)(row0+q)*128 + col] = (__bf16)(sv[q] * p.c1[      col] + p.c2[      col]);
                    p.o1[(long)(row0+q)*128 + col] = (__bf16)(sv[q] * p.c1[256 + col] + p.c2[256 + col]);
                    p.o2[(long)(row0+q)*128 + col] = (__bf16)(sv[q] * p.c1[128 + col] + p.c2[128 + col]);
                }
                bf16x4 lk;
                #pragma unroll
                for (int q = 0; q < 4; q++) lk[q] = (__bf16)(sv[q] * p.c1[384 + col] + p.c2[384 + col]);
                *(bf16x4*)(p.o3 + (long)col*16384 + row0) = lk;
            }
        }
    }
}

// ---------------- merged SIM + LINKV (one dispatch, 768 blocks) ----------------
// blocks [0,256): attn = relu(qq@qk^T/256 + bias)^2, (bx,by,z) = (id&1,(id>>1)&1,id>>2)
// blocks [256,768): lin_kv split-K partials, (by,z) = (t&15, t>>4)
__global__ __launch_bounds__(256, 2) void simlinkv_kernel(GP ps, GP pl) {
    __shared__ __bf16 As[128*32];
    __shared__ __bf16 Bs[128*32];
    int id = blockIdx.x;
    bool sim = id < 256;
    GP p = sim ? ps : pl;
    int bx, by, z;
    if (sim) { bx = id & 1; by = (id >> 1) & 1; z = id >> 2; }
    else     { int t = id - 256; bx = 0; by = t & 15; z = t >> 4; }

    const __bf16* A = p.A + (long)z * p.sAz + (long)bx * 128 * p.lda;
    const __bf16* B = p.B + (long)z * p.sBz + (long)by * 128 * p.ldb;
    int tid = threadIdx.x;
    int wave = tid >> 6, lane = tid & 63;
    int wr = (wave >> 1) * 64, wc = (wave & 1) * 64;
    int lr = lane & 15, kg = lane >> 4;

    f32x4 acc[4][4] = {};

    int lsub = lane >> 2;
    int scol = (lane & 3) * 8;
    const __bf16* Ag = A + scol + (long)(wave*32 + lsub) * p.lda;
    const __bf16* Bg = B + scol + (long)(wave*32 + lsub) * p.ldb;
    long a16 = (long)16 * p.lda, b16 = (long)16 * p.ldb;
    __bf16* AsW = As + wave * 32 * 32;
    __bf16* BsW = Bs + wave * 32 * 32;

    for (int ks = 0; ks < p.kSteps; ++ks) {
        long k0 = (long)ks * 32;
        __syncthreads();
        gload16(Ag + k0,       (const char*)AsW);
        gload16(Ag + k0 + a16, (const char*)(AsW + 16*32));
        gload16(Bg + k0,       (const char*)BsW);
        gload16(Bg + k0 + b16, (const char*)(BsW + 16*32));
        __syncthreads();
        bf16x8 af[4], bfr[4];
        #pragma unroll
        for (int i = 0; i < 4; i++) af[i]  = *(const bf16x8*)(As + (wr + i*16 + lr)*32 + kg*8);
        #pragma unroll
        for (int i = 0; i < 4; i++) bfr[i] = *(const bf16x8*)(Bs + (wc + i*16 + lr)*32 + kg*8);
        #pragma unroll
        for (int i = 0; i < 4; i++)
            #pragma unroll
            for (int j = 0; j < 4; j++)
                acc[i][j] = __builtin_amdgcn_mfma_f32_16x16x32_bf16(af[i], bfr[j], acc[i][j], 0, 0, 0);
    }

    #pragma unroll
    for (int i = 0; i < 4; i++) {
        #pragma unroll
        for (int j = 0; j < 4; j++) {
            int row0 = bx*128 + wr + i*16 + kg*4;
            int col  = by*128 + wc + j*16 + lr;
            if (sim) {                      // relu(acc/256 + bias)^2 -> attn
                #pragma unroll
                for (int q = 0; q < 4; q++) {
                    int row = row0 + q;
                    float s = acc[i][j][q] * (1.0f/256.0f) + p.c0[row*256 + col];
                    s = fmaxf(s, 0.0f);
                    p.o0[(long)z*p.sCz + (long)row*256 + col] = (__bf16)(s * s);
                }
            } else {                        // scaled partial, transposed store
                bf16x4 vv;
                #pragma unroll
                for (int q = 0; q < 4; q++) vv[q] = (__bf16)(acc[i][j][q] * p.scale);
                *(bf16x4*)(p.o0 + (long)z*p.sCz + (long)col*128 + row0) = vv;
            }
        }
    }
}

// ---------------- fused quad_out + lin_out + gate (in-place into gate buffer) ----------------
__global__ __launch_bounds__(256, 2) void quadlin_kernel(GP p) {
    __shared__ __bf16 As[128*32];
    __shared__ __bf16 Bs[128*32];
    int z = blockIdx.z;
    int batch = z >> 4;
    int tid = threadIdx.x;
    int wave = tid >> 6, lane = tid & 63;
    int wr = (wave >> 1) * 64, wc = (wave & 1) * 64;
    int lr = lane & 15, kg = lane >> 4;
    int lsub = lane >> 2;
    int scol = (lane & 3) * 8;
    __bf16* AsW = As + wave * 32 * 32;
    __bf16* BsW = Bs + wave * 32 * 32;

    f32x4 acc[4][4] = {};

    {
        const __bf16* Ag = p.A + (long)z * 65536 + (long)blockIdx.x * 128 * 256
                         + scol + (long)(wave*32 + lsub) * 256;
        const __bf16* Bg = p.B + (long)z * 256 + (long)blockIdx.y * 128 * 16384
                         + scol + (long)(wave*32 + lsub) * 16384;
        for (int ks = 0; ks < 8; ++ks) {
            long k0 = (long)ks * 32;
            __syncthreads();
            gload16(Ag + k0,             (const char*)AsW);
            gload16(Ag + k0 + 16*256,    (const char*)(AsW + 16*32));
            gload16(Bg + k0,             (const char*)BsW);
            gload16(Bg + k0 + 16L*16384, (const char*)(BsW + 16*32));
            __syncthreads();
            bf16x8 af[4], bfr[4];
            #pragma unroll
            for (int i = 0; i < 4; i++) af[i]  = *(const bf16x8*)(As + (wr + i*16 + lr)*32 + kg*8);
            #pragma unroll
            for (int i = 0; i < 4; i++) bfr[i] = *(const bf16x8*)(Bs + (wc + i*16 + lr)*32 + kg*8);
            #pragma unroll
            for (int i = 0; i < 4; i++)
                #pragma unroll
                for (int j = 0; j < 4; j++)
                    acc[i][j] = __builtin_amdgcn_mfma_f32_16x16x32_bf16(af[i], bfr[j], acc[i][j], 0, 0, 0);
        }
    }
    {
        const __bf16* Ag = p.A2 + ((long)z * 256 + (long)blockIdx.x * 128) * 128
                         + scol + (long)(wave*32 + lsub) * 128;
        const __bf16* Bg = p.B2 + (long)batch * 2048 * 128 + (long)blockIdx.y * 128 * 128
                         + scol + (long)(wave*32 + lsub) * 128;
        for (int ks = 0; ks < 4; ++ks) {
            long k0 = (long)ks * 32;
            __syncthreads();
            gload16(Ag + k0,          (const char*)AsW);
            gload16(Ag + k0 + 16*128, (const char*)(AsW + 16*32));
            gload16(Bg + k0,          (const char*)BsW);
            gload16(Bg + k0 + 16*128, (const char*)(BsW + 16*32));
            __syncthreads();
            bf16x8 af[4], bfr[4];
            #pragma unroll
            for (int i = 0; i < 4; i++) af[i]  = *(const bf16x8*)(As + (wr + i*16 + lr)*32 + kg*8);
            #pragma unroll
            for (int i = 0; i < 4; i++) bfr[i] = *(const bf16x8*)(Bs + (wc + i*16 + lr)*32 + kg*8);
            #pragma unroll
            for (int i = 0; i < 4; i++)
                #pragma unroll
                for (int j = 0; j < 4; j++)
                    acc[i][j] = __builtin_amdgcn_mfma_f32_16x16x32_bf16(af[i], bfr[j], acc[i][j], 0, 0, 0);
        }
    }
    #pragma unroll
    for (int i = 0; i < 4; i++) {
        #pragma unroll
        for (int j = 0; j < 4; j++) {
            int row0 = z*256 + blockIdx.x*128 + wr + i*16 + kg*4;
            int col  = blockIdx.y*128 + wc + j*16 + lr;
            #pragma unroll
            for (int q = 0; q < 4; q++) {
                long idx = (long)(row0+q)*2048 + col;
                float g = (float)p.gbuf[idx];
                p.gbuf[idx] = (__bf16)(g * acc[i][j][q]);
            }
        }
    }
}

extern "C" void kernel_launch(void* const* d_in, const int* in_sizes, int n_in,
                              void* d_out, int out_size, void* d_ws, size_t ws_size,
                              hipStream_t stream) {
    const float* x       = (const float*)d_in[0];
    const float* ln_g    = (const float*)d_in[1];
    const float* ln_b    = (const float*)d_in[2];
    const float* W_h     = (const float*)d_in[3];
    const float* b_h     = (const float*)d_in[4];
    const float* W_qk    = (const float*)d_in[5];
    const float* b_qk    = (const float*)d_in[6];
    const float* os_g    = (const float*)d_in[7];
    const float* os_b    = (const float*)d_in[8];
    const float* rel_emb = (const float*)d_in[9];
    const float* W_o     = (const float*)d_in[10];
    const float* b_o     = (const float*)d_in[11];
    float* out = (float*)d_out;

    const size_t MB = 1024 * 1024;
    if (ws_size < 190 * MB) return;

    char* ws = (char*)d_ws;
    __bf16* gate = (__bf16*)(ws + 0);          // 64 MB
    __bf16* vT   = (__bf16*)(ws + 64*MB);      // 64 MB
    __bf16* norm = (__bf16*)(ws + 128*MB);     // 32 MB (dead after gemm<1>)
    __bf16* attn = (__bf16*)(ws + 128*MB);     //  8 MB (aliases norm)
    __bf16* lkvT = (__bf16*)(ws + 136*MB);     //  2 MB (aliases norm)
    __bf16* lkvP = (__bf16*)(ws + 140*MB);     // 16 MB split-K partials (aliases norm)
    __bf16* qq   = (__bf16*)(ws + 160*MB);
    __bf16* qk2  = (__bf16*)(ws + 164*MB);
    __bf16* lq   = (__bf16*)(ws + 168*MB);
    __bf16* lkT  = (__bf16*)(ws + 172*MB);
    float*  bmat = (float* )(ws + 176*MB);
    __bf16* WqkT = (__bf16*)(ws + 176*MB + 256*1024);
    __bf16* WoT  = (__bf16*)(ws + 177*MB);
    __bf16* WhT  = (__bf16*)(ws + 181*MB);

    prep_kernel<<<6528, 256, 0, stream>>>(W_h, W_qk, W_o, rel_emb, WhT, WqkT, WoT, bmat);
    ln_kernel<<<16384, 256, 0, stream>>>(x, ln_g, ln_b, norm);

    // hidden = silu(norm @ W_h + b_h): v -> vT (e-major), gate token-major  [128^2 BK=64]
    {
        GP p{}; p.A = norm; p.B = WhT; p.lda = 1024; p.ldb = 1024; p.kSteps = 16;
        p.c0 = b_h; p.o0 = vT; p.o1 = gate;
        gemm64_kernel<0><<<dim3(128, 32), 256, 0, stream>>>(p);
    }
    // qk = silu(norm @ W_qk + b_qk) -> quad_q, quad_k, lin_q, lin_k^T
    {
        GP p{}; p.A = norm; p.B = WqkT; p.lda = 1024; p.ldb = 1024; p.kSteps = 32;
        p.c0 = b_qk; p.c1 = os_g; p.c2 = os_b;
        p.o0 = qq; p.o1 = qk2; p.o2 = lq; p.o3 = lkT;
        gemm_kernel<1><<<dim3(128, 1, 1), 256, 0, stream>>>(p);
    }
    // merged: attn (256 blocks) + lin_kv split-K partials (512 blocks)
    {
        GP ps{}; ps.A = qq; ps.B = qk2; ps.lda = 128; ps.ldb = 128; ps.kSteps = 4;
        ps.sAz = 256*128; ps.sBz = 256*128; ps.sCz = 256*256;
        ps.c0 = bmat; ps.o0 = attn;
        GP pl{}; pl.A = lkT; pl.B = vT; pl.lda = 16384; pl.ldb = 16384; pl.kSteps = 16;
        pl.sAz = 512; pl.sBz = 512; pl.sCz = 2048*128; pl.scale = 1.0f/4096.0f;
        pl.o0 = lkvP;
        simlinkv_kernel<<<768, 256, 0, stream>>>(ps, pl);
    }
    reduce8_kernel<<<1024, 256, 0, stream>>>(lkvP, lkvT);
    // gate <- gate * (attn @ v + lin_q @ lin_kv)
    {
        GP p{}; p.A = attn; p.B = vT; p.A2 = lq; p.B2 = lkvT; p.gbuf = gate;
        quadlin_kernel<<<dim3(2, 16, 64), 256, 0, stream>>>(p);
    }
    // final = combined @ W_o + b_o + x   [128^2 BK=64]
    {
        GP p{}; p.A = gate; p.B = WoT; p.lda = 2048; p.ldb = 2048; p.kSteps = 32;
        p.c0 = b_o; p.c1 = x; p.outF = out;
        gemm64_kernel<6><<<dim3(128, 8), 256, 0, stream>>>(p);
    }
}

// Round 12
// 412.068 us; speedup vs baseline: 3.9042x; 1.0523x over previous
//
#include <hip/hip_runtime.h>
#include <hip/hip_bf16.h>

typedef float  f32x4  __attribute__((ext_vector_type(4)));
typedef __bf16 bf16x8 __attribute__((ext_vector_type(8)));
typedef __bf16 bf16x4 __attribute__((ext_vector_type(4)));

__device__ __forceinline__ float silu_f(float x) { return x / (1.0f + __expf(-x)); }

__device__ __forceinline__ void gload16(const __bf16* g, const char* lds) {
    __builtin_amdgcn_global_load_lds((const __attribute__((address_space(1))) void*)g,
                                     (__attribute__((address_space(3))) void*)lds, 16, 0, 0);
}

// ---------------- merged LN + weight transposes + rel-bias ----------------
// blocks [0,16384): LayerNorm rows; [16384,20480): W_h T; [20480,20608): W_qk T;
// [20608,22656): W_o T; [22656,22912): relbias.
__global__ __launch_bounds__(256) void prepln_kernel(const float* __restrict__ x,
                                                     const float* __restrict__ ln_g,
                                                     const float* __restrict__ ln_b,
                                                     __bf16* __restrict__ norm,
                                                     const float* __restrict__ W_h,
                                                     const float* __restrict__ W_qk,
                                                     const float* __restrict__ W_o,
                                                     const float* __restrict__ rel_emb,
                                                     __bf16* __restrict__ WhT,
                                                     __bf16* __restrict__ WqkT,
                                                     __bf16* __restrict__ WoT,
                                                     float* __restrict__ bmat) {
    __shared__ float red[8];
    __shared__ __bf16 tile[32][33];
    int id = blockIdx.x, tid = threadIdx.x;
    if (id < 16384) {                       // LayerNorm
        const float* xr = x + (long)id * 1024;
        f32x4 v = *(const f32x4*)(xr + tid * 4);
        float s  = v[0] + v[1] + v[2] + v[3];
        float ss = v[0]*v[0] + v[1]*v[1] + v[2]*v[2] + v[3]*v[3];
        #pragma unroll
        for (int off = 32; off > 0; off >>= 1) {
            s  += __shfl_down(s, off);
            ss += __shfl_down(ss, off);
        }
        int wave = tid >> 6, lane = tid & 63;
        if (lane == 0) { red[wave*2] = s; red[wave*2+1] = ss; }
        __syncthreads();
        float S  = red[0] + red[2] + red[4] + red[6];
        float SS = red[1] + red[3] + red[5] + red[7];
        float mean = S * (1.0f/1024.0f);
        float var  = SS * (1.0f/1024.0f) - mean*mean;
        float rstd = rsqrtf(var + 1e-5f);
        __bf16* orow = norm + (long)id * 1024;
        #pragma unroll
        for (int j = 0; j < 4; j++) {
            float fv = (v[j] - mean) * rstd * ln_g[tid*4+j] + ln_b[tid*4+j];
            orow[tid*4+j] = (__bf16)fv;
        }
        return;
    }
    id -= 16384;
    if (id >= 6272) {                       // relbias
        int idx = (id - 6272) * 256 + tid;
        int i = idx >> 8, j = idx & 255;
        int n = i - j;
        int ret = (n < 0) ? 16 : 0;
        int an = (n < 0) ? -n : n;
        int bucket;
        if (an < 8) {
            bucket = ret + an;
        } else {
            float vl = logf((float)an * 0.125f) / 2.772588722239781f * 8.0f;
            int lv = 8 + (int)vl;
            bucket = ret + (lv < 15 ? lv : 15);
        }
        bmat[idx] = rel_emb[bucket] * 11.313708498984761f;
        return;
    }
    const float* in; __bf16* outp; int rows, cols, tx, ty;
    if (id < 4096)      { in = W_h;  outp = WhT;  rows = 1024; cols = 4096; tx = id % 128; ty = id / 128; }
    else if (id < 4224) { int t = id - 4096; in = W_qk; outp = WqkT; rows = 1024; cols = 128;  tx = t % 4;  ty = t / 4; }
    else                { int t = id - 4224; in = W_o;  outp = WoT;  rows = 2048; cols = 1024; tx = t % 32; ty = t / 32; }
    int c0 = tx * 32, r0 = ty * 32;
    int lx = tid & 31, ly = tid >> 5;
    #pragma unroll
    for (int i = 0; i < 4; i++) {
        int r = ly + i*8;
        tile[r][lx] = (__bf16)in[(long)(r0 + r) * cols + c0 + lx];
    }
    __syncthreads();
    #pragma unroll
    for (int i = 0; i < 4; i++) {
        int c = ly + i*8;
        outp[(long)(c0 + c) * rows + r0 + lx] = tile[lx][c];
    }
}

// ---------------- reduce 8 bf16 partials -> bf16 ----------------
__global__ __launch_bounds__(256) void reduce8_kernel(const __bf16* __restrict__ in,
                                                      __bf16* __restrict__ out) {
    int i = (blockIdx.x * 256 + threadIdx.x) * 4;
    int b = i >> 18;
    int r = i & 262143;
    float s0 = 0.f, s1 = 0.f, s2 = 0.f, s3 = 0.f;
    #pragma unroll
    for (int c = 0; c < 8; ++c) {
        bf16x4 v = *(const bf16x4*)(in + ((long)(b*8 + c) << 18) + r);
        s0 += (float)v[0]; s1 += (float)v[1]; s2 += (float)v[2]; s3 += (float)v[3];
    }
    bf16x4 o; o[0] = (__bf16)s0; o[1] = (__bf16)s1; o[2] = (__bf16)s2; o[3] = (__bf16)s3;
    *(bf16x4*)(out + i) = o;
}

// ---------------- GP param block ----------------
struct GP {
    const __bf16* A;
    const __bf16* B;
    const __bf16* A2;
    const __bf16* B2;
    int lda, ldb, kSteps;
    long sAz, sBz, sCz;
    float scale;
    float* outF;
    __bf16 *o0, *o1, *o2, *o3, *o4, *o5;
    const float *c0, *c1, *c2, *c3;
    __bf16* gbuf;
};

// ================= merged H + QK GEMM (128x128, BK=64), grid (128, 33) =================
// by<32: hidden = silu(norm@W_h+b_h) -> vT/gate.  by==32: qk = silu(norm@WqkT+b_qk) -> 4 heads.
// Both K=1024 (16 steps), lda=ldb=1024.
__global__ __launch_bounds__(256, 2) void hqk_kernel(GP p) {
    __shared__ __bf16 As[2*128*32];
    __shared__ __bf16 Bs[2*128*32];
    int bx = blockIdx.x, by = blockIdx.y;
    bool qkm = (by == 32);
    const __bf16* A = p.A + (long)bx * 128 * 1024;
    const __bf16* B = qkm ? p.B2 : p.B + (long)by * 128 * 1024;
    int tid = threadIdx.x;
    int wave = tid >> 6, lane = tid & 63;
    int wr = (wave >> 1) * 64, wc = (wave & 1) * 64;
    int lr = lane & 15, kg = lane >> 4;

    f32x4 acc[4][4] = {};

    int lsub = lane >> 2;
    int scol = (lane & 3) * 8;
    const __bf16* Ag = A + scol + (long)(wave*32 + lsub) * 1024;
    const __bf16* Bg = B + scol + (long)(wave*32 + lsub) * 1024;
    const long s16 = 16 * 1024;
    __bf16* AsW = As + wave * 32 * 32;
    __bf16* BsW = Bs + wave * 32 * 32;

    for (int ks = 0; ks < 16; ++ks) {
        long k0 = (long)ks * 64;
        __syncthreads();
        gload16(Ag + k0,            (const char*)AsW);
        gload16(Ag + k0 + s16,      (const char*)(AsW + 16*32));
        gload16(Bg + k0,            (const char*)BsW);
        gload16(Bg + k0 + s16,      (const char*)(BsW + 16*32));
        gload16(Ag + k0 + 32,       (const char*)(AsW + 4096));
        gload16(Ag + k0 + 32 + s16, (const char*)(AsW + 4096 + 16*32));
        gload16(Bg + k0 + 32,       (const char*)(BsW + 4096));
        gload16(Bg + k0 + 32 + s16, (const char*)(BsW + 4096 + 16*32));
        __syncthreads();
#pragma unroll
        for (int kk = 0; kk < 2; ++kk) {
            bf16x8 af[4], bfr[4];
            #pragma unroll
            for (int i = 0; i < 4; i++) af[i]  = *(const bf16x8*)(As + kk*4096 + (wr + i*16 + lr)*32 + kg*8);
            #pragma unroll
            for (int i = 0; i < 4; i++) bfr[i] = *(const bf16x8*)(Bs + kk*4096 + (wc + i*16 + lr)*32 + kg*8);
            #pragma unroll
            for (int i = 0; i < 4; i++)
                #pragma unroll
                for (int j = 0; j < 4; j++)
                    acc[i][j] = __builtin_amdgcn_mfma_f32_16x16x32_bf16(af[i], bfr[j], acc[i][j], 0, 0, 0);
        }
    }

    #pragma unroll
    for (int i = 0; i < 4; i++) {
        #pragma unroll
        for (int j = 0; j < 4; j++) {
            int row0 = bx*128 + wr + i*16 + kg*4;
            if (!qkm) {
                int col = by*128 + wc + j*16 + lr;
                if (col < 2048) {
                    bf16x4 vv;
                    #pragma unroll
                    for (int q = 0; q < 4; q++) vv[q] = (__bf16)silu_f(acc[i][j][q] + p.c0[col]);
                    *(bf16x4*)(p.o0 + (long)col*16384 + row0) = vv;     // vT[e][t]
                } else {
                    #pragma unroll
                    for (int q = 0; q < 4; q++)
                        p.o1[(long)(row0+q)*2048 + (col - 2048)] = (__bf16)silu_f(acc[i][j][q] + p.c0[col]);
                }
            } else {
                int col = wc + j*16 + lr;                               // 0..127
                float sv[4];
                #pragma unroll
                for (int q = 0; q < 4; q++) sv[q] = silu_f(acc[i][j][q] + p.c3[col]);
                #pragma unroll
                for (int q = 0; q < 4; q++) {
                    p.o2[(long)(row0+q)*128 + col] = (__bf16)(sv[q] * p.c1[      col] + p.c2[      col]);  // quad_q
                    p.o3[(long)(row0+q)*128 + col] = (__bf16)(sv[q] * p.c1[256 + col] + p.c2[256 + col]);  // quad_k
                    p.o4[(long)(row0+q)*128 + col] = (__bf16)(sv[q] * p.c1[128 + col] + p.c2[128 + col]);  // lin_q
                }
                bf16x4 lk;
                #pragma unroll
                for (int q = 0; q < 4; q++) lk[q] = (__bf16)(sv[q] * p.c1[384 + col] + p.c2[384 + col]);
                *(bf16x4*)(p.o5 + (long)col*16384 + row0) = lk;         // lkT[d][t]
            }
        }
    }
}

// ================= 128x128 GEMM, BK=64 — FINAL epilogue =================
__global__ __launch_bounds__(256, 2) void gemm64f_kernel(GP p) {
    __shared__ __bf16 As[2*128*32];
    __shared__ __bf16 Bs[2*128*32];
    const __bf16* A = p.A + (long)blockIdx.x * 128 * p.lda;
    const __bf16* B = p.B + (long)blockIdx.y * 128 * p.ldb;
    int tid = threadIdx.x;
    int wave = tid >> 6, lane = tid & 63;
    int wr = (wave >> 1) * 64, wc = (wave & 1) * 64;
    int lr = lane & 15, kg = lane >> 4;

    f32x4 acc[4][4] = {};

    int lsub = lane >> 2;
    int scol = (lane & 3) * 8;
    const __bf16* Ag = A + scol + (long)(wave*32 + lsub) * p.lda;
    const __bf16* Bg = B + scol + (long)(wave*32 + lsub) * p.ldb;
    long a16 = (long)16 * p.lda, b16 = (long)16 * p.ldb;
    __bf16* AsW = As + wave * 32 * 32;
    __bf16* BsW = Bs + wave * 32 * 32;

    for (int ks = 0; ks < p.kSteps; ++ks) {
        long k0 = (long)ks * 64;
        __syncthreads();
        gload16(Ag + k0,            (const char*)AsW);
        gload16(Ag + k0 + a16,      (const char*)(AsW + 16*32));
        gload16(Bg + k0,            (const char*)BsW);
        gload16(Bg + k0 + b16,      (const char*)(BsW + 16*32));
        gload16(Ag + k0 + 32,       (const char*)(AsW + 4096));
        gload16(Ag + k0 + 32 + a16, (const char*)(AsW + 4096 + 16*32));
        gload16(Bg + k0 + 32,       (const char*)(BsW + 4096));
        gload16(Bg + k0 + 32 + b16, (const char*)(BsW + 4096 + 16*32));
        __syncthreads();
#pragma unroll
        for (int kk = 0; kk < 2; ++kk) {
            bf16x8 af[4], bfr[4];
            #pragma unroll
            for (int i = 0; i < 4; i++) af[i]  = *(const bf16x8*)(As + kk*4096 + (wr + i*16 + lr)*32 + kg*8);
            #pragma unroll
            for (int i = 0; i < 4; i++) bfr[i] = *(const bf16x8*)(Bs + kk*4096 + (wc + i*16 + lr)*32 + kg*8);
            #pragma unroll
            for (int i = 0; i < 4; i++)
                #pragma unroll
                for (int j = 0; j < 4; j++)
                    acc[i][j] = __builtin_amdgcn_mfma_f32_16x16x32_bf16(af[i], bfr[j], acc[i][j], 0, 0, 0);
        }
    }

    int bx = blockIdx.x, by = blockIdx.y;
    #pragma unroll
    for (int i = 0; i < 4; i++) {
        #pragma unroll
        for (int j = 0; j < 4; j++) {
            int row0 = bx*128 + wr + i*16 + kg*4;
            int col  = by*128 + wc + j*16 + lr;
            #pragma unroll
            for (int q = 0; q < 4; q++) {
                long idx = (long)(row0+q)*1024 + col;
                p.outF[idx] = acc[i][j][q] + p.c0[col] + p.c1[idx];
            }
        }
    }
}

// ---------------- merged SIM + LINKV (BK=64, one dispatch, 768 blocks) ----------------
// blocks [0,256): attn = relu(qq@qk^T/256 + bias)^2, K=128 (2 steps)
// blocks [256,768): lin_kv split-K partials, K=512 (8 steps)
__global__ __launch_bounds__(256, 2) void simlinkv_kernel(GP ps, GP pl) {
    __shared__ __bf16 As[2*128*32];
    __shared__ __bf16 Bs[2*128*32];
    int id = blockIdx.x;
    bool sim = id < 256;
    GP p = sim ? ps : pl;
    int bx, by, z;
    if (sim) { bx = id & 1; by = (id >> 1) & 1; z = id >> 2; }
    else     { int t = id - 256; bx = 0; by = t & 15; z = t >> 4; }

    const __bf16* A = p.A + (long)z * p.sAz + (long)bx * 128 * p.lda;
    const __bf16* B = p.B + (long)z * p.sBz + (long)by * 128 * p.ldb;
    int tid = threadIdx.x;
    int wave = tid >> 6, lane = tid & 63;
    int wr = (wave >> 1) * 64, wc = (wave & 1) * 64;
    int lr = lane & 15, kg = lane >> 4;

    f32x4 acc[4][4] = {};

    int lsub = lane >> 2;
    int scol = (lane & 3) * 8;
    const __bf16* Ag = A + scol + (long)(wave*32 + lsub) * p.lda;
    const __bf16* Bg = B + scol + (long)(wave*32 + lsub) * p.ldb;
    long a16 = (long)16 * p.lda, b16 = (long)16 * p.ldb;
    __bf16* AsW = As + wave * 32 * 32;
    __bf16* BsW = Bs + wave * 32 * 32;

    for (int ks = 0; ks < p.kSteps; ++ks) {
        long k0 = (long)ks * 64;
        __syncthreads();
        gload16(Ag + k0,            (const char*)AsW);
        gload16(Ag + k0 + a16,      (const char*)(AsW + 16*32));
        gload16(Bg + k0,            (const char*)BsW);
        gload16(Bg + k0 + b16,      (const char*)(BsW + 16*32));
        gload16(Ag + k0 + 32,       (const char*)(AsW + 4096));
        gload16(Ag + k0 + 32 + a16, (const char*)(AsW + 4096 + 16*32));
        gload16(Bg + k0 + 32,       (const char*)(BsW + 4096));
        gload16(Bg + k0 + 32 + b16, (const char*)(BsW + 4096 + 16*32));
        __syncthreads();
#pragma unroll
        for (int kk = 0; kk < 2; ++kk) {
            bf16x8 af[4], bfr[4];
            #pragma unroll
            for (int i = 0; i < 4; i++) af[i]  = *(const bf16x8*)(As + kk*4096 + (wr + i*16 + lr)*32 + kg*8);
            #pragma unroll
            for (int i = 0; i < 4; i++) bfr[i] = *(const bf16x8*)(Bs + kk*4096 + (wc + i*16 + lr)*32 + kg*8);
            #pragma unroll
            for (int i = 0; i < 4; i++)
                #pragma unroll
                for (int j = 0; j < 4; j++)
                    acc[i][j] = __builtin_amdgcn_mfma_f32_16x16x32_bf16(af[i], bfr[j], acc[i][j], 0, 0, 0);
        }
    }

    #pragma unroll
    for (int i = 0; i < 4; i++) {
        #pragma unroll
        for (int j = 0; j < 4; j++) {
            int row0 = bx*128 + wr + i*16 + kg*4;
            int col  = by*128 + wc + j*16 + lr;
            if (sim) {
                #pragma unroll
                for (int q = 0; q < 4; q++) {
                    int row = row0 + q;
                    float s = acc[i][j][q] * (1.0f/256.0f) + p.c0[row*256 + col];
                    s = fmaxf(s, 0.0f);
                    p.o0[(long)z*p.sCz + (long)row*256 + col] = (__bf16)(s * s);
                }
            } else {
                bf16x4 vv;
                #pragma unroll
                for (int q = 0; q < 4; q++) vv[q] = (__bf16)(acc[i][j][q] * p.scale);
                *(bf16x4*)(p.o0 + (long)z*p.sCz + (long)col*128 + row0) = vv;
            }
        }
    }
}

// ---------------- fused quad_out + lin_out + gate (BK=64, in-place into gate) ----------------
__global__ __launch_bounds__(256, 2) void quadlin_kernel(GP p) {
    __shared__ __bf16 As[2*128*32];
    __shared__ __bf16 Bs[2*128*32];
    int z = blockIdx.z;
    int batch = z >> 4;
    int tid = threadIdx.x;
    int wave = tid >> 6, lane = tid & 63;
    int wr = (wave >> 1) * 64, wc = (wave & 1) * 64;
    int lr = lane & 15, kg = lane >> 4;
    int lsub = lane >> 2;
    int scol = (lane & 3) * 8;
    __bf16* AsW = As + wave * 32 * 32;
    __bf16* BsW = Bs + wave * 32 * 32;

    f32x4 acc[4][4] = {};

    // pass 1: attn (lda 256) @ vT (ldb 16384), K = 256 -> 4 steps of 64
    {
        const __bf16* Ag = p.A + (long)z * 65536 + (long)blockIdx.x * 128 * 256
                         + scol + (long)(wave*32 + lsub) * 256;
        const __bf16* Bg = p.B + (long)z * 256 + (long)blockIdx.y * 128 * 16384
                         + scol + (long)(wave*32 + lsub) * 16384;
        const long a16 = 16*256, b16 = 16L*16384;
        for (int ks = 0; ks < 4; ++ks) {
            long k0 = (long)ks * 64;
            __syncthreads();
            gload16(Ag + k0,            (const char*)AsW);
            gload16(Ag + k0 + a16,      (const char*)(AsW + 16*32));
            gload16(Bg + k0,            (const char*)BsW);
            gload16(Bg + k0 + b16,      (const char*)(BsW + 16*32));
            gload16(Ag + k0 + 32,       (const char*)(AsW + 4096));
            gload16(Ag + k0 + 32 + a16, (const char*)(AsW + 4096 + 16*32));
            gload16(Bg + k0 + 32,       (const char*)(BsW + 4096));
            gload16(Bg + k0 + 32 + b16, (const char*)(BsW + 4096 + 16*32));
            __syncthreads();
#pragma unroll
            for (int kk = 0; kk < 2; ++kk) {
                bf16x8 af[4], bfr[4];
                #pragma unroll
                for (int i = 0; i < 4; i++) af[i]  = *(const bf16x8*)(As + kk*4096 + (wr + i*16 + lr)*32 + kg*8);
                #pragma unroll
                for (int i = 0; i < 4; i++) bfr[i] = *(const bf16x8*)(Bs + kk*4096 + (wc + i*16 + lr)*32 + kg*8);
                #pragma unroll
                for (int i = 0; i < 4; i++)
                    #pragma unroll
                    for (int j = 0; j < 4; j++)
                        acc[i][j] = __builtin_amdgcn_mfma_f32_16x16x32_bf16(af[i], bfr[j], acc[i][j], 0, 0, 0);
            }
        }
    }
    // pass 2: lin_q (lda 128) @ lkvT (ldb 128), K = 128 -> 2 steps of 64
    {
        const __bf16* Ag = p.A2 + ((long)z * 256 + (long)blockIdx.x * 128) * 128
                         + scol + (long)(wave*32 + lsub) * 128;
        const __bf16* Bg = p.B2 + (long)batch * 2048 * 128 + (long)blockIdx.y * 128 * 128
                         + scol + (long)(wave*32 + lsub) * 128;
        const long a16 = 16*128, b16 = 16*128;
        for (int ks = 0; ks < 2; ++ks) {
            long k0 = (long)ks * 64;
            __syncthreads();
            gload16(Ag + k0,            (const char*)AsW);
            gload16(Ag + k0 + a16,      (const char*)(AsW + 16*32));
            gload16(Bg + k0,            (const char*)BsW);
            gload16(Bg + k0 + b16,      (const char*)(BsW + 16*32));
            gload16(Ag + k0 + 32,       (const char*)(AsW + 4096));
            gload16(Ag + k0 + 32 + a16, (const char*)(AsW + 4096 + 16*32));
            gload16(Bg + k0 + 32,       (const char*)(BsW + 4096));
            gload16(Bg + k0 + 32 + b16, (const char*)(BsW + 4096 + 16*32));
            __syncthreads();
#pragma unroll
            for (int kk = 0; kk < 2; ++kk) {
                bf16x8 af[4], bfr[4];
                #pragma unroll
                for (int i = 0; i < 4; i++) af[i]  = *(const bf16x8*)(As + kk*4096 + (wr + i*16 + lr)*32 + kg*8);
                #pragma unroll
                for (int i = 0; i < 4; i++) bfr[i] = *(const bf16x8*)(Bs + kk*4096 + (wc + i*16 + lr)*32 + kg*8);
                #pragma unroll
                for (int i = 0; i < 4; i++)
                    #pragma unroll
                    for (int j = 0; j < 4; j++)
                        acc[i][j] = __builtin_amdgcn_mfma_f32_16x16x32_bf16(af[i], bfr[j], acc[i][j], 0, 0, 0);
            }
        }
    }
    #pragma unroll
    for (int i = 0; i < 4; i++) {
        #pragma unroll
        for (int j = 0; j < 4; j++) {
            int row0 = z*256 + blockIdx.x*128 + wr + i*16 + kg*4;
            int col  = blockIdx.y*128 + wc + j*16 + lr;
            #pragma unroll
            for (int q = 0; q < 4; q++) {
                long idx = (long)(row0+q)*2048 + col;
                float g = (float)p.gbuf[idx];
                p.gbuf[idx] = (__bf16)(g * acc[i][j][q]);
            }
        }
    }
}

extern "C" void kernel_launch(void* const* d_in, const int* in_sizes, int n_in,
                              void* d_out, int out_size, void* d_ws, size_t ws_size,
                              hipStream_t stream) {
    const float* x       = (const float*)d_in[0];
    const float* ln_g    = (const float*)d_in[1];
    const float* ln_b    = (const float*)d_in[2];
    const float* W_h     = (const float*)d_in[3];
    const float* b_h     = (const float*)d_in[4];
    const float* W_qk    = (const float*)d_in[5];
    const float* b_qk    = (const float*)d_in[6];
    const float* os_g    = (const float*)d_in[7];
    const float* os_b    = (const float*)d_in[8];
    const float* rel_emb = (const float*)d_in[9];
    const float* W_o     = (const float*)d_in[10];
    const float* b_o     = (const float*)d_in[11];
    float* out = (float*)d_out;

    const size_t MB = 1024 * 1024;
    if (ws_size < 190 * MB) return;

    char* ws = (char*)d_ws;
    __bf16* gate = (__bf16*)(ws + 0);          // 64 MB
    __bf16* vT   = (__bf16*)(ws + 64*MB);      // 64 MB
    __bf16* norm = (__bf16*)(ws + 128*MB);     // 32 MB (dead after hqk)
    __bf16* attn = (__bf16*)(ws + 128*MB);     //  8 MB (aliases norm)
    __bf16* lkvT = (__bf16*)(ws + 136*MB);     //  2 MB (aliases norm)
    __bf16* lkvP = (__bf16*)(ws + 140*MB);     // 16 MB split-K partials (aliases norm)
    __bf16* qq   = (__bf16*)(ws + 160*MB);
    __bf16* qk2  = (__bf16*)(ws + 164*MB);
    __bf16* lq   = (__bf16*)(ws + 168*MB);
    __bf16* lkT  = (__bf16*)(ws + 172*MB);
    float*  bmat = (float* )(ws + 176*MB);
    __bf16* WqkT = (__bf16*)(ws + 176*MB + 256*1024);
    __bf16* WoT  = (__bf16*)(ws + 177*MB);
    __bf16* WhT  = (__bf16*)(ws + 181*MB);

    // LN + weight prep + relbias, one dispatch
    prepln_kernel<<<22912, 256, 0, stream>>>(x, ln_g, ln_b, norm,
                                             W_h, W_qk, W_o, rel_emb,
                                             WhT, WqkT, WoT, bmat);

    // merged: hidden (by<32) + qk heads (by==32)
    {
        GP p{}; p.A = norm; p.B = WhT; p.B2 = WqkT;
        p.c0 = b_h; p.o0 = vT; p.o1 = gate;
        p.c3 = b_qk; p.c1 = os_g; p.c2 = os_b;
        p.o2 = qq; p.o3 = qk2; p.o4 = lq; p.o5 = lkT;
        hqk_kernel<<<dim3(128, 33), 256, 0, stream>>>(p);
    }
    // merged: attn (256 blocks, K=128) + lin_kv split-K partials (512 blocks, K=512)
    {
        GP ps{}; ps.A = qq; ps.B = qk2; ps.lda = 128; ps.ldb = 128; ps.kSteps = 2;
        ps.sAz = 256*128; ps.sBz = 256*128; ps.sCz = 256*256;
        ps.c0 = bmat; ps.o0 = attn;
        GP pl{}; pl.A = lkT; pl.B = vT; pl.lda = 16384; pl.ldb = 16384; pl.kSteps = 8;
        pl.sAz = 512; pl.sBz = 512; pl.sCz = 2048*128; pl.scale = 1.0f/4096.0f;
        pl.o0 = lkvP;
        simlinkv_kernel<<<768, 256, 0, stream>>>(ps, pl);
    }
    reduce8_kernel<<<1024, 256, 0, stream>>>(lkvP, lkvT);
    // gate <- gate * (attn @ v + lin_q @ lin_kv)
    {
        GP p{}; p.A = attn; p.B = vT; p.A2 = lq; p.B2 = lkvT; p.gbuf = gate;
        quadlin_kernel<<<dim3(2, 16, 64), 256, 0, stream>>>(p);
    }
    // final = combined @ W_o + b_o + x   [128^2 BK=64]
    {
        GP p{}; p.A = gate; p.B = WoT; p.lda = 2048; p.ldb = 2048; p.kSteps = 32;
        p.c0 = b_o; p.c1 = x; p.outF = out;
        gemm64f_kernel<<<dim3(128, 8), 256, 0, stream>>>(p);
    }
}

// Round 13
// 406.417 us; speedup vs baseline: 3.9585x; 1.0139x over previous
//
#include <hip/hip_runtime.h>
#include <hip/hip_bf16.h>

typedef float  f32x4  __attribute__((ext_vector_type(4)));
typedef __bf16 bf16x8 __attribute__((ext_vector_type(8)));
typedef __bf16 bf16x4 __attribute__((ext_vector_type(4)));

__device__ __forceinline__ float silu_f(float x) { return x / (1.0f + __expf(-x)); }

__device__ __forceinline__ void gload16(const __bf16* g, const char* lds) {
    __builtin_amdgcn_global_load_lds((const __attribute__((address_space(1))) void*)g,
                                     (__attribute__((address_space(3))) void*)lds, 16, 0, 0);
}

// ---------------- merged LN + weight transposes + rel-bias ----------------
__global__ __launch_bounds__(256) void prepln_kernel(const float* __restrict__ x,
                                                     const float* __restrict__ ln_g,
                                                     const float* __restrict__ ln_b,
                                                     __bf16* __restrict__ norm,
                                                     const float* __restrict__ W_h,
                                                     const float* __restrict__ W_qk,
                                                     const float* __restrict__ W_o,
                                                     const float* __restrict__ rel_emb,
                                                     __bf16* __restrict__ WhT,
                                                     __bf16* __restrict__ WqkT,
                                                     __bf16* __restrict__ WoT,
                                                     float* __restrict__ bmat) {
    __shared__ float red[8];
    __shared__ __bf16 tile[32][33];
    int id = blockIdx.x, tid = threadIdx.x;
    if (id < 16384) {                       // LayerNorm
        const float* xr = x + (long)id * 1024;
        f32x4 v = *(const f32x4*)(xr + tid * 4);
        float s  = v[0] + v[1] + v[2] + v[3];
        float ss = v[0]*v[0] + v[1]*v[1] + v[2]*v[2] + v[3]*v[3];
        #pragma unroll
        for (int off = 32; off > 0; off >>= 1) {
            s  += __shfl_down(s, off);
            ss += __shfl_down(ss, off);
        }
        int wave = tid >> 6, lane = tid & 63;
        if (lane == 0) { red[wave*2] = s; red[wave*2+1] = ss; }
        __syncthreads();
        float S  = red[0] + red[2] + red[4] + red[6];
        float SS = red[1] + red[3] + red[5] + red[7];
        float mean = S * (1.0f/1024.0f);
        float var  = SS * (1.0f/1024.0f) - mean*mean;
        float rstd = rsqrtf(var + 1e-5f);
        __bf16* orow = norm + (long)id * 1024;
        #pragma unroll
        for (int j = 0; j < 4; j++) {
            float fv = (v[j] - mean) * rstd * ln_g[tid*4+j] + ln_b[tid*4+j];
            orow[tid*4+j] = (__bf16)fv;
        }
        return;
    }
    id -= 16384;
    if (id >= 6272) {                       // relbias
        int idx = (id - 6272) * 256 + tid;
        int i = idx >> 8, j = idx & 255;
        int n = i - j;
        int ret = (n < 0) ? 16 : 0;
        int an = (n < 0) ? -n : n;
        int bucket;
        if (an < 8) {
            bucket = ret + an;
        } else {
            float vl = logf((float)an * 0.125f) / 2.772588722239781f * 8.0f;
            int lv = 8 + (int)vl;
            bucket = ret + (lv < 15 ? lv : 15);
        }
        bmat[idx] = rel_emb[bucket] * 11.313708498984761f;
        return;
    }
    const float* in; __bf16* outp; int rows, cols, tx, ty;
    if (id < 4096)      { in = W_h;  outp = WhT;  rows = 1024; cols = 4096; tx = id % 128; ty = id / 128; }
    else if (id < 4224) { int t = id - 4096; in = W_qk; outp = WqkT; rows = 1024; cols = 128;  tx = t % 4;  ty = t / 4; }
    else                { int t = id - 4224; in = W_o;  outp = WoT;  rows = 2048; cols = 1024; tx = t % 32; ty = t / 32; }
    int c0 = tx * 32, r0 = ty * 32;
    int lx = tid & 31, ly = tid >> 5;
    #pragma unroll
    for (int i = 0; i < 4; i++) {
        int r = ly + i*8;
        tile[r][lx] = (__bf16)in[(long)(r0 + r) * cols + c0 + lx];
    }
    __syncthreads();
    #pragma unroll
    for (int i = 0; i < 4; i++) {
        int c = ly + i*8;
        outp[(long)(c0 + c) * rows + r0 + lx] = tile[lx][c];
    }
}

// ---------------- reduce 8 bf16 partials -> bf16 ----------------
__global__ __launch_bounds__(256) void reduce8_kernel(const __bf16* __restrict__ in,
                                                      __bf16* __restrict__ out) {
    int i = (blockIdx.x * 256 + threadIdx.x) * 4;
    int b = i >> 18;
    int r = i & 262143;
    float s0 = 0.f, s1 = 0.f, s2 = 0.f, s3 = 0.f;
    #pragma unroll
    for (int c = 0; c < 8; ++c) {
        bf16x4 v = *(const bf16x4*)(in + ((long)(b*8 + c) << 18) + r);
        s0 += (float)v[0]; s1 += (float)v[1]; s2 += (float)v[2]; s3 += (float)v[3];
    }
    bf16x4 o; o[0] = (__bf16)s0; o[1] = (__bf16)s1; o[2] = (__bf16)s2; o[3] = (__bf16)s3;
    *(bf16x4*)(out + i) = o;
}

// ---------------- GP param block ----------------
struct GP {
    const __bf16* A;
    const __bf16* B;
    const __bf16* A2;
    const __bf16* B2;
    int lda, ldb, kSteps;
    long sAz, sBz, sCz;
    float scale;
    float* outF;
    __bf16 *o0, *o1, *o2, *o3, *o4, *o5;
    const float *c0, *c1, *c2, *c3;
    __bf16* gbuf;
};

// ================= merged H + QK GEMM (128x128, BK=64), grid (128, 33) =================
// L2-blocking XCD map: xcd = id&7 owns bx in [xcd*16, xcd*16+16) (A-footprint 16x256KB
// = 4MB = one XCD L2) and iterates by over them -> A re-reads become L2 hits.
__global__ __launch_bounds__(256, 2) void hqk_kernel(GP p) {
    __shared__ __bf16 As[2*128*32];
    __shared__ __bf16 Bs[2*128*32];
    int id = blockIdx.y * 128 + blockIdx.x;
    int xcd = id & 7, seq = id >> 3;        // seq 0..527
    int by = seq >> 4;                      // 0..32
    int bx = (xcd << 4) | (seq & 15);       // 0..127
    bool qkm = (by == 32);
    const __bf16* A = p.A + (long)bx * 128 * 1024;
    const __bf16* B = qkm ? p.B2 : p.B + (long)by * 128 * 1024;
    int tid = threadIdx.x;
    int wave = tid >> 6, lane = tid & 63;
    int wr = (wave >> 1) * 64, wc = (wave & 1) * 64;
    int lr = lane & 15, kg = lane >> 4;

    f32x4 acc[4][4] = {};

    int lsub = lane >> 2;
    int scol = (lane & 3) * 8;
    const __bf16* Ag = A + scol + (long)(wave*32 + lsub) * 1024;
    const __bf16* Bg = B + scol + (long)(wave*32 + lsub) * 1024;
    const long s16 = 16 * 1024;
    __bf16* AsW = As + wave * 32 * 32;
    __bf16* BsW = Bs + wave * 32 * 32;

    for (int ks = 0; ks < 16; ++ks) {
        long k0 = (long)ks * 64;
        __syncthreads();
        gload16(Ag + k0,            (const char*)AsW);
        gload16(Ag + k0 + s16,      (const char*)(AsW + 16*32));
        gload16(Bg + k0,            (const char*)BsW);
        gload16(Bg + k0 + s16,      (const char*)(BsW + 16*32));
        gload16(Ag + k0 + 32,       (const char*)(AsW + 4096));
        gload16(Ag + k0 + 32 + s16, (const char*)(AsW + 4096 + 16*32));
        gload16(Bg + k0 + 32,       (const char*)(BsW + 4096));
        gload16(Bg + k0 + 32 + s16, (const char*)(BsW + 4096 + 16*32));
        __syncthreads();
#pragma unroll
        for (int kk = 0; kk < 2; ++kk) {
            bf16x8 af[4], bfr[4];
            #pragma unroll
            for (int i = 0; i < 4; i++) af[i]  = *(const bf16x8*)(As + kk*4096 + (wr + i*16 + lr)*32 + kg*8);
            #pragma unroll
            for (int i = 0; i < 4; i++) bfr[i] = *(const bf16x8*)(Bs + kk*4096 + (wc + i*16 + lr)*32 + kg*8);
            #pragma unroll
            for (int i = 0; i < 4; i++)
                #pragma unroll
                for (int j = 0; j < 4; j++)
                    acc[i][j] = __builtin_amdgcn_mfma_f32_16x16x32_bf16(af[i], bfr[j], acc[i][j], 0, 0, 0);
        }
    }

    #pragma unroll
    for (int i = 0; i < 4; i++) {
        #pragma unroll
        for (int j = 0; j < 4; j++) {
            int row0 = bx*128 + wr + i*16 + kg*4;
            if (!qkm) {
                int col = by*128 + wc + j*16 + lr;
                if (col < 2048) {
                    bf16x4 vv;
                    #pragma unroll
                    for (int q = 0; q < 4; q++) vv[q] = (__bf16)silu_f(acc[i][j][q] + p.c0[col]);
                    *(bf16x4*)(p.o0 + (long)col*16384 + row0) = vv;     // vT[e][t]
                } else {
                    #pragma unroll
                    for (int q = 0; q < 4; q++)
                        p.o1[(long)(row0+q)*2048 + (col - 2048)] = (__bf16)silu_f(acc[i][j][q] + p.c0[col]);
                }
            } else {
                int col = wc + j*16 + lr;                               // 0..127
                float sv[4];
                #pragma unroll
                for (int q = 0; q < 4; q++) sv[q] = silu_f(acc[i][j][q] + p.c3[col]);
                #pragma unroll
                for (int q = 0; q < 4; q++) {
                    p.o2[(long)(row0+q)*128 + col] = (__bf16)(sv[q] * p.c1[      col] + p.c2[      col]);  // quad_q
                    p.o3[(long)(row0+q)*128 + col] = (__bf16)(sv[q] * p.c1[256 + col] + p.c2[256 + col]);  // quad_k
                    p.o4[(long)(row0+q)*128 + col] = (__bf16)(sv[q] * p.c1[128 + col] + p.c2[128 + col]);  // lin_q
                }
                bf16x4 lk;
                #pragma unroll
                for (int q = 0; q < 4; q++) lk[q] = (__bf16)(sv[q] * p.c1[384 + col] + p.c2[384 + col]);
                *(bf16x4*)(p.o5 + (long)col*16384 + row0) = lk;         // lkT[d][t]
            }
        }
    }
}

// ================= 128x128 GEMM BK=64 — FINAL epilogue, L2-blocked XCD map =================
// A-panels are 512KB -> per-XCD group of 8 bx (4MB) L2-resident across all 8 by; 2 groups.
__global__ __launch_bounds__(256, 2) void gemm64f_kernel(GP p) {
    __shared__ __bf16 As[2*128*32];
    __shared__ __bf16 Bs[2*128*32];
    int id = blockIdx.y * 128 + blockIdx.x;
    int xcd = id & 7, seq = id >> 3;        // seq 0..127
    int grp = seq >> 6;                     // 0..1
    int by  = (seq >> 3) & 7;               // 0..7
    int bx  = (xcd << 4) | (grp << 3) | (seq & 7);   // 0..127
    const __bf16* A = p.A + (long)bx * 128 * p.lda;
    const __bf16* B = p.B + (long)by * 128 * p.ldb;
    int tid = threadIdx.x;
    int wave = tid >> 6, lane = tid & 63;
    int wr = (wave >> 1) * 64, wc = (wave & 1) * 64;
    int lr = lane & 15, kg = lane >> 4;

    f32x4 acc[4][4] = {};

    int lsub = lane >> 2;
    int scol = (lane & 3) * 8;
    const __bf16* Ag = A + scol + (long)(wave*32 + lsub) * p.lda;
    const __bf16* Bg = B + scol + (long)(wave*32 + lsub) * p.ldb;
    long a16 = (long)16 * p.lda, b16 = (long)16 * p.ldb;
    __bf16* AsW = As + wave * 32 * 32;
    __bf16* BsW = Bs + wave * 32 * 32;

    for (int ks = 0; ks < p.kSteps; ++ks) {
        long k0 = (long)ks * 64;
        __syncthreads();
        gload16(Ag + k0,            (const char*)AsW);
        gload16(Ag + k0 + a16,      (const char*)(AsW + 16*32));
        gload16(Bg + k0,            (const char*)BsW);
        gload16(Bg + k0 + b16,      (const char*)(BsW + 16*32));
        gload16(Ag + k0 + 32,       (const char*)(AsW + 4096));
        gload16(Ag + k0 + 32 + a16, (const char*)(AsW + 4096 + 16*32));
        gload16(Bg + k0 + 32,       (const char*)(BsW + 4096));
        gload16(Bg + k0 + 32 + b16, (const char*)(BsW + 4096 + 16*32));
        __syncthreads();
#pragma unroll
        for (int kk = 0; kk < 2; ++kk) {
            bf16x8 af[4], bfr[4];
            #pragma unroll
            for (int i = 0; i < 4; i++) af[i]  = *(const bf16x8*)(As + kk*4096 + (wr + i*16 + lr)*32 + kg*8);
            #pragma unroll
            for (int i = 0; i < 4; i++) bfr[i] = *(const bf16x8*)(Bs + kk*4096 + (wc + i*16 + lr)*32 + kg*8);
            #pragma unroll
            for (int i = 0; i < 4; i++)
                #pragma unroll
                for (int j = 0; j < 4; j++)
                    acc[i][j] = __builtin_amdgcn_mfma_f32_16x16x32_bf16(af[i], bfr[j], acc[i][j], 0, 0, 0);
        }
    }

    #pragma unroll
    for (int i = 0; i < 4; i++) {
        #pragma unroll
        for (int j = 0; j < 4; j++) {
            int row0 = bx*128 + wr + i*16 + kg*4;
            int col  = by*128 + wc + j*16 + lr;
            #pragma unroll
            for (int q = 0; q < 4; q++) {
                long idx = (long)(row0+q)*1024 + col;
                p.outF[idx] = acc[i][j][q] + p.c0[col] + p.c1[idx];
            }
        }
    }
}

// ---------------- merged SIM + LINKV (BK=64, one dispatch, 768 blocks) ----------------
__global__ __launch_bounds__(256, 2) void simlinkv_kernel(GP ps, GP pl) {
    __shared__ __bf16 As[2*128*32];
    __shared__ __bf16 Bs[2*128*32];
    int id = blockIdx.x;
    bool sim = id < 256;
    GP p = sim ? ps : pl;
    int bx, by, z;
    if (sim) { bx = id & 1; by = (id >> 1) & 1; z = id >> 2; }
    else     { int t = id - 256; bx = 0; by = t & 15; z = t >> 4; }

    const __bf16* A = p.A + (long)z * p.sAz + (long)bx * 128 * p.lda;
    const __bf16* B = p.B + (long)z * p.sBz + (long)by * 128 * p.ldb;
    int tid = threadIdx.x;
    int wave = tid >> 6, lane = tid & 63;
    int wr = (wave >> 1) * 64, wc = (wave & 1) * 64;
    int lr = lane & 15, kg = lane >> 4;

    f32x4 acc[4][4] = {};

    int lsub = lane >> 2;
    int scol = (lane & 3) * 8;
    const __bf16* Ag = A + scol + (long)(wave*32 + lsub) * p.lda;
    const __bf16* Bg = B + scol + (long)(wave*32 + lsub) * p.ldb;
    long a16 = (long)16 * p.lda, b16 = (long)16 * p.ldb;
    __bf16* AsW = As + wave * 32 * 32;
    __bf16* BsW = Bs + wave * 32 * 32;

    for (int ks = 0; ks < p.kSteps; ++ks) {
        long k0 = (long)ks * 64;
        __syncthreads();
        gload16(Ag + k0,            (const char*)AsW);
        gload16(Ag + k0 + a16,      (const char*)(AsW + 16*32));
        gload16(Bg + k0,            (const char*)BsW);
        gload16(Bg + k0 + b16,      (const char*)(BsW + 16*32));
        gload16(Ag + k0 + 32,       (const char*)(AsW + 4096));
        gload16(Ag + k0 + 32 + a16, (const char*)(AsW + 4096 + 16*32));
        gload16(Bg + k0 + 32,       (const char*)(BsW + 4096));
        gload16(Bg + k0 + 32 + b16, (const char*)(BsW + 4096 + 16*32));
        __syncthreads();
#pragma unroll
        for (int kk = 0; kk < 2; ++kk) {
            bf16x8 af[4], bfr[4];
            #pragma unroll
            for (int i = 0; i < 4; i++) af[i]  = *(const bf16x8*)(As + kk*4096 + (wr + i*16 + lr)*32 + kg*8);
            #pragma unroll
            for (int i = 0; i < 4; i++) bfr[i] = *(const bf16x8*)(Bs + kk*4096 + (wc + i*16 + lr)*32 + kg*8);
            #pragma unroll
            for (int i = 0; i < 4; i++)
                #pragma unroll
                for (int j = 0; j < 4; j++)
                    acc[i][j] = __builtin_amdgcn_mfma_f32_16x16x32_bf16(af[i], bfr[j], acc[i][j], 0, 0, 0);
        }
    }

    #pragma unroll
    for (int i = 0; i < 4; i++) {
        #pragma unroll
        for (int j = 0; j < 4; j++) {
            int row0 = bx*128 + wr + i*16 + kg*4;
            int col  = by*128 + wc + j*16 + lr;
            if (sim) {
                #pragma unroll
                for (int q = 0; q < 4; q++) {
                    int row = row0 + q;
                    float s = acc[i][j][q] * (1.0f/256.0f) + p.c0[row*256 + col];
                    s = fmaxf(s, 0.0f);
                    p.o0[(long)z*p.sCz + (long)row*256 + col] = (__bf16)(s * s);
                }
            } else {
                bf16x4 vv;
                #pragma unroll
                for (int q = 0; q < 4; q++) vv[q] = (__bf16)(acc[i][j][q] * p.scale);
                *(bf16x4*)(p.o0 + (long)z*p.sCz + (long)col*128 + row0) = vv;
            }
        }
    }
}

// ---------------- fused quad_out + lin_out + gate (BK=64, in-place into gate) ----------------
__global__ __launch_bounds__(256, 2) void quadlin_kernel(GP p) {
    __shared__ __bf16 As[2*128*32];
    __shared__ __bf16 Bs[2*128*32];
    int z = blockIdx.z;
    int batch = z >> 4;
    int tid = threadIdx.x;
    int wave = tid >> 6, lane = tid & 63;
    int wr = (wave >> 1) * 64, wc = (wave & 1) * 64;
    int lr = lane & 15, kg = lane >> 4;
    int lsub = lane >> 2;
    int scol = (lane & 3) * 8;
    __bf16* AsW = As + wave * 32 * 32;
    __bf16* BsW = Bs + wave * 32 * 32;

    f32x4 acc[4][4] = {};

    // pass 1: attn (lda 256) @ vT (ldb 16384), K = 256 -> 4 steps of 64
    {
        const __bf16* Ag = p.A + (long)z * 65536 + (long)blockIdx.x * 128 * 256
                         + scol + (long)(wave*32 + lsub) * 256;
        const __bf16* Bg = p.B + (long)z * 256 + (long)blockIdx.y * 128 * 16384
                         + scol + (long)(wave*32 + lsub) * 16384;
        const long a16 = 16*256, b16 = 16L*16384;
        for (int ks = 0; ks < 4; ++ks) {
            long k0 = (long)ks * 64;
            __syncthreads();
            gload16(Ag + k0,            (const char*)AsW);
            gload16(Ag + k0 + a16,      (const char*)(AsW + 16*32));
            gload16(Bg + k0,            (const char*)BsW);
            gload16(Bg + k0 + b16,      (const char*)(BsW + 16*32));
            gload16(Ag + k0 + 32,       (const char*)(AsW + 4096));
            gload16(Ag + k0 + 32 + a16, (const char*)(AsW + 4096 + 16*32));
            gload16(Bg + k0 + 32,       (const char*)(BsW + 4096));
            gload16(Bg + k0 + 32 + b16, (const char*)(BsW + 4096 + 16*32));
            __syncthreads();
#pragma unroll
            for (int kk = 0; kk < 2; ++kk) {
                bf16x8 af[4], bfr[4];
                #pragma unroll
                for (int i = 0; i < 4; i++) af[i]  = *(const bf16x8*)(As + kk*4096 + (wr + i*16 + lr)*32 + kg*8);
                #pragma unroll
                for (int i = 0; i < 4; i++) bfr[i] = *(const bf16x8*)(Bs + kk*4096 + (wc + i*16 + lr)*32 + kg*8);
                #pragma unroll
                for (int i = 0; i < 4; i++)
                    #pragma unroll
                    for (int j = 0; j < 4; j++)
                        acc[i][j] = __builtin_amdgcn_mfma_f32_16x16x32_bf16(af[i], bfr[j], acc[i][j], 0, 0, 0);
            }
        }
    }
    // pass 2: lin_q (lda 128) @ lkvT (ldb 128), K = 128 -> 2 steps of 64
    {
        const __bf16* Ag = p.A2 + ((long)z * 256 + (long)blockIdx.x * 128) * 128
                         + scol + (long)(wave*32 + lsub) * 128;
        const __bf16* Bg = p.B2 + (long)batch * 2048 * 128 + (long)blockIdx.y * 128 * 128
                         + scol + (long)(wave*32 + lsub) * 128;
        const long a16 = 16*128, b16 = 16*128;
        for (int ks = 0; ks < 2; ++ks) {
            long k0 = (long)ks * 64;
            __syncthreads();
            gload16(Ag + k0,            (const char*)AsW);
            gload16(Ag + k0 + a16,      (const char*)(AsW + 16*32));
            gload16(Bg + k0,            (const char*)BsW);
            gload16(Bg + k0 + b16,      (const char*)(BsW + 16*32));
            gload16(Ag + k0 + 32,       (const char*)(AsW + 4096));
            gload16(Ag + k0 + 32 + a16, (const char*)(AsW + 4096 + 16*32));
            gload16(Bg + k0 + 32,       (const char*)(BsW + 4096));
            gload16(Bg + k0 + 32 + b16, (const char*)(BsW + 4096 + 16*32));
            __syncthreads();
#pragma unroll
            for (int kk = 0; kk < 2; ++kk) {
                bf16x8 af[4], bfr[4];
                #pragma unroll
                for (int i = 0; i < 4; i++) af[i]  = *(const bf16x8*)(As + kk*4096 + (wr + i*16 + lr)*32 + kg*8);
                #pragma unroll
                for (int i = 0; i < 4; i++) bfr[i] = *(const bf16x8*)(Bs + kk*4096 + (wc + i*16 + lr)*32 + kg*8);
                #pragma unroll
                for (int i = 0; i < 4; i++)
                    #pragma unroll
                    for (int j = 0; j < 4; j++)
                        acc[i][j] = __builtin_amdgcn_mfma_f32_16x16x32_bf16(af[i], bfr[j], acc[i][j], 0, 0, 0);
            }
        }
    }
    #pragma unroll
    for (int i = 0; i < 4; i++) {
        #pragma unroll
        for (int j = 0; j < 4; j++) {
            int row0 = z*256 + blockIdx.x*128 + wr + i*16 + kg*4;
            int col  = blockIdx.y*128 + wc + j*16 + lr;
            #pragma unroll
            for (int q = 0; q < 4; q++) {
                long idx = (long)(row0+q)*2048 + col;
                float g = (float)p.gbuf[idx];
                p.gbuf[idx] = (__bf16)(g * acc[i][j][q]);
            }
        }
    }
}

extern "C" void kernel_launch(void* const* d_in, const int* in_sizes, int n_in,
                              void* d_out, int out_size, void* d_ws, size_t ws_size,
                              hipStream_t stream) {
    const float* x       = (const float*)d_in[0];
    const float* ln_g    = (const float*)d_in[1];
    const float* ln_b    = (const float*)d_in[2];
    const float* W_h     = (const float*)d_in[3];
    const float* b_h     = (const float*)d_in[4];
    const float* W_qk    = (const float*)d_in[5];
    const float* b_qk    = (const float*)d_in[6];
    const float* os_g    = (const float*)d_in[7];
    const float* os_b    = (const float*)d_in[8];
    const float* rel_emb = (const float*)d_in[9];
    const float* W_o     = (const float*)d_in[10];
    const float* b_o     = (const float*)d_in[11];
    float* out = (float*)d_out;

    const size_t MB = 1024 * 1024;
    if (ws_size < 190 * MB) return;

    char* ws = (char*)d_ws;
    __bf16* gate = (__bf16*)(ws + 0);          // 64 MB
    __bf16* vT   = (__bf16*)(ws + 64*MB);      // 64 MB
    __bf16* norm = (__bf16*)(ws + 128*MB);     // 32 MB (dead after hqk)
    __bf16* attn = (__bf16*)(ws + 128*MB);     //  8 MB (aliases norm)
    __bf16* lkvT = (__bf16*)(ws + 136*MB);     //  2 MB (aliases norm)
    __bf16* lkvP = (__bf16*)(ws + 140*MB);     // 16 MB split-K partials (aliases norm)
    __bf16* qq   = (__bf16*)(ws + 160*MB);
    __bf16* qk2  = (__bf16*)(ws + 164*MB);
    __bf16* lq   = (__bf16*)(ws + 168*MB);
    __bf16* lkT  = (__bf16*)(ws + 172*MB);
    float*  bmat = (float* )(ws + 176*MB);
    __bf16* WqkT = (__bf16*)(ws + 176*MB + 256*1024);
    __bf16* WoT  = (__bf16*)(ws + 177*MB);
    __bf16* WhT  = (__bf16*)(ws + 181*MB);

    // LN + weight prep + relbias, one dispatch
    prepln_kernel<<<22912, 256, 0, stream>>>(x, ln_g, ln_b, norm,
                                             W_h, W_qk, W_o, rel_emb,
                                             WhT, WqkT, WoT, bmat);

    // merged: hidden (by<32) + qk heads (by==32), L2-blocked XCD map
    {
        GP p{}; p.A = norm; p.B = WhT; p.B2 = WqkT;
        p.c0 = b_h; p.o0 = vT; p.o1 = gate;
        p.c3 = b_qk; p.c1 = os_g; p.c2 = os_b;
        p.o2 = qq; p.o3 = qk2; p.o4 = lq; p.o5 = lkT;
        hqk_kernel<<<dim3(128, 33), 256, 0, stream>>>(p);
    }
    // merged: attn (256 blocks, K=128) + lin_kv split-K partials (512 blocks, K=512)
    {
        GP ps{}; ps.A = qq; ps.B = qk2; ps.lda = 128; ps.ldb = 128; ps.kSteps = 2;
        ps.sAz = 256*128; ps.sBz = 256*128; ps.sCz = 256*256;
        ps.c0 = bmat; ps.o0 = attn;
        GP pl{}; pl.A = lkT; pl.B = vT; pl.lda = 16384; pl.ldb = 16384; pl.kSteps = 8;
        pl.sAz = 512; pl.sBz = 512; pl.sCz = 2048*128; pl.scale = 1.0f/4096.0f;
        pl.o0 = lkvP;
        simlinkv_kernel<<<768, 256, 0, stream>>>(ps, pl);
    }
    reduce8_kernel<<<1024, 256, 0, stream>>>(lkvP, lkvT);
    // gate <- gate * (attn @ v + lin_q @ lin_kv)
    {
        GP p{}; p.A = attn; p.B = vT; p.A2 = lq; p.B2 = lkvT; p.gbuf = gate;
        quadlin_kernel<<<dim3(2, 16, 64), 256, 0, stream>>>(p);
    }
    // final = combined @ W_o + b_o + x   [128^2 BK=64, L2-blocked XCD map]
    {
        GP p{}; p.A = gate; p.B = WoT; p.lda = 2048; p.ldb = 2048; p.kSteps = 32;
        p.c0 = b_o; p.c1 = x; p.outF = out;
        gemm64f_kernel<<<dim3(128, 8), 256, 0, stream>>>(p);
    }
}